// Round 4
// baseline (472.755 us; speedup 1.0000x reference)
//
#include <hip/hip_runtime.h>
#include <hip/hip_cooperative_groups.h>

namespace cg = cooperative_groups;

typedef unsigned short u16;
typedef short s16x8 __attribute__((ext_vector_type(8)));
typedef u16 u16x4 __attribute__((ext_vector_type(4)));
typedef float f32x4 __attribute__((ext_vector_type(4)));

#define B_ 32
#define L_ 256
#define D_ 1024
#define H_ 8
#define DQ_ 128
#define DS_ 64
#define DM_ 256
#define DF_ 4096

__device__ __forceinline__ u16 f2bf(float f) {
  unsigned u = __float_as_uint(f);
  unsigned r = (u + 0x7FFFu + ((u >> 16) & 1u)) >> 16;
  return (u16)r;
}
__device__ __forceinline__ float bf2f(u16 x) {
  return __uint_as_float(((unsigned)x) << 16);
}

__device__ __forceinline__ f32x4 mfma16(s16x8 a, s16x8 b, f32x4 c) {
  return __builtin_amdgcn_mfma_f32_16x16x32_bf16(a, b, c, 0, 0, 0);
}

#define GLDS16(g, l)                                                        \
  __builtin_amdgcn_global_load_lds(                                         \
      (__attribute__((address_space(1))) const void*)(g),                   \
      (__attribute__((address_space(3))) void*)(l), 16, 0, 0)

// ---------------- 32x32 transpose+convert tile helper
__device__ __forceinline__ void tile_tr(const float* __restrict__ ip,
                                        u16* __restrict__ op, int K, int N,
                                        int bx, int by, float (*t)[33], int tid) {
  const int tx = tid & 31, ty = tid >> 5;
  const long n0 = (long)bx * 32, k0 = (long)by * 32;
#pragma unroll
  for (int i = 0; i < 4; ++i)
    t[ty + i * 8][tx] = ip[(k0 + ty + i * 8) * (long)N + n0 + tx];
  __syncthreads();
#pragma unroll
  for (int i = 0; i < 4; ++i)
    op[(n0 + ty + i * 8) * (long)K + k0 + tx] = f2bf(t[tx][ty + i * 8]);
}

// ---------------- phase 1 mega-kernel: all weight transposes + src conv + hid
// grid: [0,3072) qkvT | [3072,4096) owT | [4096,8192) w1T | [8192,12288) w2T |
//       [12288,12544) conv src b0 | [12544,12552) hid (block 12544 also zeros qhead)
__global__ __launch_bounds__(256) void prep(
    const float* __restrict__ qw, const float* __restrict__ kw,
    const float* __restrict__ vw, const float* __restrict__ ow,
    const float* __restrict__ w1, const float* __restrict__ w2,
    const float* __restrict__ src, const float* __restrict__ sf,
    const float* __restrict__ b1w, const float* __restrict__ b1b,
    u16* __restrict__ qwT, u16* __restrict__ kwT, u16* __restrict__ vwT,
    u16* __restrict__ owT, u16* __restrict__ w1T, u16* __restrict__ w2T,
    u16* __restrict__ src0b, float* __restrict__ nzv, int* __restrict__ nzi,
    int* __restrict__ nzcnt, int* __restrict__ qhead) {
  const int b = blockIdx.x;
  const int tid = threadIdx.x;
  __shared__ float t[32][33];
  __shared__ float s_sf[DS_];
  __shared__ int wcnt[4];
  if (b < 3072) {
    const int z = b >> 7, rem = b & 127;
    const int sel = z >> 3, h = z & 7;
    const float* ip = (sel == 0 ? qw : (sel == 1 ? kw : vw)) + (long)h * D_ * DQ_;
    u16* op = (sel == 0 ? qwT : (sel == 1 ? kwT : vwT)) + (long)h * DQ_ * D_;
    tile_tr(ip, op, D_, DQ_, rem & 3, rem >> 2, t, tid);
  } else if (b < 4096) {
    const int rem = b - 3072;
    tile_tr(ow, owT, D_, D_, rem & 31, rem >> 5, t, tid);
  } else if (b < 8192) {
    const int rem = b - 4096;
    tile_tr(w1, w1T, D_, DF_, rem & 127, rem >> 7, t, tid);
  } else if (b < 12288) {
    const int rem = b - 8192;
    tile_tr(w2, w2T, DF_, D_, rem & 31, rem >> 5, t, tid);
  } else if (b < 12544) {
    const int rem = b - 12288;
    const int i = (rem * 256 + tid) * 4;
    float4 v = *(const float4*)(src + i);
    u16x4 o = {f2bf(v.x), f2bf(v.y), f2bf(v.z), f2bf(v.w)};
    *(u16x4*)(src0b + i) = o;
  } else {
    const int h = b - 12544;
    if (h == 0 && tid == 0) *qhead = 0;  // reset mid's work queue (stream-ordered)
    if (tid < DS_) s_sf[tid] = sf[tid];
    __syncthreads();
    float a = b1b[h * DM_ + tid];
    const float* wp = b1w + (long)h * DS_ * DM_ + tid;
#pragma unroll 8
    for (int s = 0; s < DS_; ++s) a += s_sf[s] * wp[s * DM_];
    a = fmaxf(a, 0.f);
    const unsigned long long bal = __ballot(a > 0.f);
    const int lane = tid & 63, wv = tid >> 6;
    const int pc = __popcll(bal);
    if (lane == 0) wcnt[wv] = pc;
    __syncthreads();
    int base = 0;
    for (int i = 0; i < wv; ++i) base += wcnt[i];
    const int pos = base + __popcll(bal & ((1ull << lane) - 1ull));
    if (a > 0.f) { nzv[h * DM_ + pos] = a; nzi[h * DM_ + pos] = tid; }
    if (tid == 255) nzcnt[h] = base + pc;
  }
}

// ---------------- mid kernel args
struct MidArgs {
  const float* nzv; const int* nzi; const int* nzcnt;
  const float* b2w; const float* b2b; float* biasb;
  const u16* src0b; const u16* qwT; const u16* kwT; const u16* vwT;
  const float* qb; const float* kb; const float* vb;
  u16* q0; u16* k0; u16* v0T;
  const int* mask; u16* hidden;
  const u16* owT; const float* ob; float* attnvec;
  const float* src; const float* ln1g; const float* ln1b; u16* xb;
  int* qhead;
};

// ---------------- shared 128x128xK m97 GEMM core (A,BT pre-offset to tile)
__device__ __forceinline__ void g128_core(const u16* __restrict__ A,
                                          const u16* __restrict__ BT, int K,
                                          u16* smA, u16* smB,
                                          f32x4 (&acc)[4][4]) {
  const int tid = threadIdx.x;
  const int lane = tid & 63;
  const int wv = tid >> 6;
  const int wr = wv >> 1, wc = wv & 1;
  const u16* ga = A + (long)(tid >> 2) * K + (tid & 3) * 8;
  const u16* gb = BT + (long)(tid >> 2) * K + (tid & 3) * 8;
  const long rstep = 64L * K;
  u16* la = &smA[tid * 8];
  u16* lb = &smB[tid * 8];
#pragma unroll
  for (int m = 0; m < 4; ++m)
#pragma unroll
    for (int n = 0; n < 4; ++n) acc[m][n] = (f32x4){0.f, 0.f, 0.f, 0.f};
  for (int k0 = 0; k0 < K; k0 += 32) {
    GLDS16(ga + k0, la);
    GLDS16(ga + rstep + k0, la + 64 * 32);
    GLDS16(gb + k0, lb);
    GLDS16(gb + rstep + k0, lb + 64 * 32);
    __syncthreads();
    s16x8 af[4], bf[4];
    const int ka = (lane >> 4) * 8;
    const int ra = wr * 64 + (lane & 15);
    const int rb = wc * 64 + (lane & 15);
#pragma unroll
    for (int m = 0; m < 4; ++m) af[m] = *(const s16x8*)&smA[(ra + m * 16) * 32 + ka];
#pragma unroll
    for (int n = 0; n < 4; ++n) bf[n] = *(const s16x8*)&smB[(rb + n * 16) * 32 + ka];
#pragma unroll
    for (int m = 0; m < 4; ++m)
#pragma unroll
      for (int n = 0; n < 4; ++n) acc[m][n] = mfma16(af[m], bf[n], acc[m][n]);
    __syncthreads();
  }
}

// ---------------- phase-A items
__device__ __forceinline__ void gemv_item(int item, const MidArgs& a,
                                          float* sv, int* si) {
  const int tid = threadIdx.x;
  const int h = item >> 6;
  const int n0 = (item & 63) << 10;
  const int nnz = a.nzcnt[h];
  sv[tid] = a.nzv[h * DM_ + tid];
  si[tid] = a.nzi[h * DM_ + tid];
  __syncthreads();
  const float* wb = a.b2w + (long)h * DM_ * 65536 + n0 + tid * 4;
  float4 acc = {0.f, 0.f, 0.f, 0.f};
  int j = 0;
  for (; j + 4 <= nnz; j += 4) {
    const float4 a0 = *(const float4*)(wb + (long)si[j] * 65536);
    const float4 a1 = *(const float4*)(wb + (long)si[j + 1] * 65536);
    const float4 a2 = *(const float4*)(wb + (long)si[j + 2] * 65536);
    const float4 a3 = *(const float4*)(wb + (long)si[j + 3] * 65536);
    const float v0 = sv[j], v1 = sv[j + 1], v2 = sv[j + 2], v3 = sv[j + 3];
    acc.x += v0 * a0.x + v1 * a1.x + v2 * a2.x + v3 * a3.x;
    acc.y += v0 * a0.y + v1 * a1.y + v2 * a2.y + v3 * a3.y;
    acc.z += v0 * a0.z + v1 * a1.z + v2 * a2.z + v3 * a3.z;
    acc.w += v0 * a0.w + v1 * a1.w + v2 * a2.w + v3 * a3.w;
  }
  for (; j < nnz; ++j) {
    const float4 a0 = *(const float4*)(wb + (long)si[j] * 65536);
    const float v0 = sv[j];
    acc.x += v0 * a0.x; acc.y += v0 * a0.y; acc.z += v0 * a0.z; acc.w += v0 * a0.w;
  }
  const float4 bb = *(const float4*)(a.b2b + (long)h * 65536 + n0 + tid * 4);
  float4 o = {acc.x + bb.x, acc.y + bb.y, acc.z + bb.z, acc.w + bb.w};
  *(float4*)(a.biasb + (long)h * 65536 + n0 + tid * 4) = o;
}

__device__ __forceinline__ void qkv_item(int r, const MidArgs& a, u16* smA,
                                         u16* smB) {
  const int tid = threadIdx.x;
  const int z = r >> 1, sel = z >> 3, h = z & 7;
  const long tm = (long)(r & 1) * 128;
  const u16* BT = (sel == 0 ? a.qwT : (sel == 1 ? a.kwT : a.vwT)) + (long)h * DQ_ * D_;
  const float* bias = (sel == 0 ? a.qb : (sel == 1 ? a.kb : a.vb)) + h * DQ_;
  f32x4 acc[4][4];
  g128_core(a.src0b + tm * D_, BT, D_, smA, smB, acc);
  const int lane = tid & 63;
  const int wv = tid >> 6;
  const int wr = wv >> 1, wc = wv & 1;
  const long crow0 = tm + wr * 64 + ((lane >> 4) * 4);
  const long ccol0 = wc * 64 + (lane & 15);
#pragma unroll
  for (int m = 0; m < 4; ++m)
#pragma unroll
    for (int n = 0; n < 4; ++n)
#pragma unroll
      for (int i = 0; i < 4; ++i) {
        const long row = crow0 + m * 16 + i;
        const long col = ccol0 + n * 16;
        const float v = acc[m][n][i] + bias[col];
        if (sel < 2) {
          u16* o = (sel == 0 ? a.q0 : a.k0) + (long)h * L_ * DQ_;
          o[row * DQ_ + col] = f2bf(v);
        } else {
          a.v0T[(long)h * DQ_ * L_ + col * L_ + row] = f2bf(v);
        }
      }
}

// ---------------- attn tile (wave 0 of a 256-thread block)
__device__ void attn_item(int item, const MidArgs& a, float* sm) {
  const int tid = threadIdx.x;
  const int h = item >> 4;
  const int r0 = (item & 15) << 4;
  const u16* q = a.q0 + (long)h * L_ * DQ_;
  const u16* k = a.k0 + (long)h * L_ * DQ_;
  const u16* v = a.v0T + (long)h * DQ_ * L_;
  const int lg = (tid >> 4) & 3;
  const int ll = tid & 15;
  float sc[16][4];
  if (tid < 64) {
    s16x8 aq[4];
#pragma unroll
    for (int kk = 0; kk < 4; ++kk)
      aq[kk] = *(const s16x8*)(q + (long)(r0 + ll) * DQ_ + kk * 32 + lg * 8);
    const float scale = 0.08838834764831845f;
#pragma unroll
    for (int t = 0; t < 16; ++t) {
      f32x4 acc = {0.f, 0.f, 0.f, 0.f};
#pragma unroll
      for (int kk = 0; kk < 4; ++kk) {
        s16x8 bf = *(const s16x8*)(k + (long)(t * 16 + ll) * DQ_ + kk * 32 + lg * 8);
        acc = mfma16(aq[kk], bf, acc);
      }
#pragma unroll
      for (int i = 0; i < 4; ++i) {
        const int row = r0 + lg * 4 + i;
        const int col = t * 16 + ll;
        float s = acc[i] * scale;
        if (a.mask[row * L_ + col] != 0) s = 1e-9f;
        sc[t][i] = s;
      }
    }
#pragma unroll
    for (int i = 0; i < 4; ++i) {
      float mx = sc[0][i];
#pragma unroll
      for (int t = 1; t < 16; ++t) mx = fmaxf(mx, sc[t][i]);
#pragma unroll
      for (int d = 1; d < 16; d <<= 1) mx = fmaxf(mx, __shfl_xor(mx, d));
      float sum = 0.f;
#pragma unroll
      for (int t = 0; t < 16; ++t) {
        const float e = __expf(sc[t][i] - mx);
        sc[t][i] = e;
        sum += e;
      }
#pragma unroll
      for (int d = 1; d < 16; d <<= 1) sum += __shfl_xor(sum, d);
      const float inv = 1.f / sum;
      const int row = r0 + lg * 4 + i;
#pragma unroll
      for (int t = 0; t < 16; ++t)
        sc[t][i] = sc[t][i] * inv + a.biasb[(long)h * 65536 + (long)row * 256 + t * 16 + ll];
    }
#pragma unroll
    for (int t = 0; t < 16; ++t)
#pragma unroll
      for (int i = 0; i < 4; ++i)
        sm[(lg * 4 + i) * 256 + t * 16 + ll] = sc[t][i];
  }
  __syncthreads();
  if (tid < 64) {
    s16x8 af[8];
#pragma unroll
    for (int kk = 0; kk < 8; ++kk) {
      const float* ap = &sm[ll * 256 + kk * 32 + lg * 8];
      s16x8 t8;
#pragma unroll
      for (int j = 0; j < 8; ++j) t8[j] = (short)f2bf(ap[j]);
      af[kk] = t8;
    }
#pragma unroll
    for (int n = 0; n < 8; ++n) {
      f32x4 acc = {0.f, 0.f, 0.f, 0.f};
#pragma unroll
      for (int kk = 0; kk < 8; ++kk) {
        s16x8 bf = *(const s16x8*)(v + (long)(n * 16 + ll) * 256 + kk * 32 + lg * 8);
        acc = mfma16(af[kk], bf, acc);
      }
#pragma unroll
      for (int i = 0; i < 4; ++i) {
        const int row = r0 + lg * 4 + i;
        const int col = n * 16 + ll;
        a.hidden[(long)row * 1024 + h * 128 + col] = f2bf(acc[i]);
      }
    }
  }
}

__device__ __forceinline__ void proj_item(int item, const MidArgs& a, u16* smA,
                                          u16* smB) {
  const int tid = threadIdx.x;
  const long tm = (long)(item >> 3) * 128;
  const long tn = (long)(item & 7) * 128;
  f32x4 acc[4][4];
  g128_core(a.hidden + tm * D_, a.owT + tn * D_, D_, smA, smB, acc);
  const int lane = tid & 63;
  const int wv = tid >> 6;
  const int wr = wv >> 1, wc = wv & 1;
  const long crow0 = tm + wr * 64 + ((lane >> 4) * 4);
  const long ccol0 = tn + wc * 64 + (lane & 15);
#pragma unroll
  for (int m = 0; m < 4; ++m)
#pragma unroll
    for (int n = 0; n < 4; ++n)
#pragma unroll
      for (int i = 0; i < 4; ++i) {
        const long row = crow0 + m * 16 + i;
        const long col = ccol0 + n * 16;
        a.attnvec[row * (long)D_ + col] = acc[m][n][i] + a.ob[col];
      }
}

__device__ __forceinline__ void ln1_rows(const MidArgs& a) {
  const int tid = threadIdx.x;
  __shared__ float ss[4], sq[4];
  for (int r = 0; r < 32; ++r) {
    const long row = (long)blockIdx.x * 32 + r;
    float4 v = ((const float4*)(a.src + row * D_))[tid];
    const float4 u = ((const float4*)(a.attnvec + (row & (L_ - 1)) * D_))[tid];
    v.x += u.x; v.y += u.y; v.z += u.z; v.w += u.w;
    float s = v.x + v.y + v.z + v.w;
    float q = v.x * v.x + v.y * v.y + v.z * v.z + v.w * v.w;
#pragma unroll
    for (int d = 1; d < 64; d <<= 1) { s += __shfl_xor(s, d); q += __shfl_xor(q, d); }
    const int wv = tid >> 6;
    if ((tid & 63) == 0) { ss[wv] = s; sq[wv] = q; }
    __syncthreads();
    s = ss[0] + ss[1] + ss[2] + ss[3];
    q = sq[0] + sq[1] + sq[2] + sq[3];
    const float mu = s * (1.f / D_);
    const float var = q * (1.f / D_) - mu * mu;
    const float rs = rsqrtf(var + 1e-5f);
    const float4 gv = ((const float4*)a.ln1g)[tid];
    const float4 bv = ((const float4*)a.ln1b)[tid];
    float4 o;
    o.x = (v.x - mu) * rs * gv.x + bv.x;
    o.y = (v.y - mu) * rs * gv.y + bv.y;
    o.z = (v.z - mu) * rs * gv.z + bv.z;
    o.w = (v.w - mu) * rs * gv.w + bv.w;
    uint2 pk;
    pk.x = (unsigned)f2bf(o.x) | ((unsigned)f2bf(o.y) << 16);
    pk.y = (unsigned)f2bf(o.z) | ((unsigned)f2bf(o.w) << 16);
    *(uint2*)(a.xb + row * D_ + tid * 4) = pk;
    __syncthreads();
  }
}

// ---------------- cooperative mid kernel: gemv+qkv | attn | proj | ln1
__global__ __launch_bounds__(256) void mid_kernel(MidArgs a) {
  __shared__ u16 smA[128 * 32];
  __shared__ u16 smB[128 * 32];
  __shared__ float sv[DM_];
  __shared__ int si[DM_];
  __shared__ float smf[16 * 256];
  __shared__ int s_item;
  const int tid = threadIdx.x;
  cg::grid_group grid = cg::this_grid();
  // phase A: work queue over 512 gemv tiles + 48 qkv tiles
  for (;;) {
    if (tid == 0)
      s_item = __hip_atomic_fetch_add(a.qhead, 1, __ATOMIC_RELAXED,
                                      __HIP_MEMORY_SCOPE_AGENT);
    __syncthreads();
    const int item = s_item;
    __syncthreads();
    if (item >= 560) break;
    if (item < 512) gemv_item(item, a, sv, si);
    else qkv_item(item - 512, a, smA, smB);
  }
  grid.sync();
  // phase B: attention (b=0), 128 blocks x 1 wave
  if (blockIdx.x < 128) attn_item(blockIdx.x, a, smf);
  grid.sync();
  // phase C: out projection, 16 x 128x128 tiles
  if (blockIdx.x < 16) proj_item(blockIdx.x, a, smA, smB);
  grid.sync();
  // phase D: LN1, 32 rows per block
  ln1_rows(a);
}

// ---------------- 8-phase 256x256 deep-pipelined GEMM (FFN1: relu + bf16 out)
__global__ __launch_bounds__(512, 2) void gemm8p_ffn1(
    const u16* __restrict__ A, const u16* __restrict__ BT, u16* __restrict__ C,
    const float* __restrict__ bias) {
  extern __shared__ char lds[];
  constexpr int BN = 256, NR = 4, BUF = 32768 + BN * 128, WST = 4;
  const int K = D_, N = DF_, ldc = DF_;
  const int tid = threadIdx.x;
  const int lane = tid & 63;
  const int w = tid >> 6;
  const int wr = w >> 2, wc = w & 3;
  const int total = gridDim.x;
  int bid = blockIdx.x;
  int s = ((total & 7) == 0) ? ((bid & 7) * (total >> 3) + (bid >> 3)) : bid;
  const int gn = N / BN;
  const long tm = (long)(s / gn) * 256;
  const long tn = (long)(s % gn) * BN;
  const int NT = K >> 6;

  auto stageA = [&](int half, int t) {
    char* hb = lds + (long)(t & 1) * BUF + half * 16384;
    const u16* g = A + (tm + half * 128) * (long)K + (long)t * 64;
#pragma unroll
    for (int j = 0; j < 2; ++j) {
      const int idx = j * 512 + tid;
      const int r = idx >> 3;
      const int c16 = (idx & 7) ^ (r & 7);
      GLDS16(g + (long)r * K + c16 * 8, hb + idx * 16);
    }
  };
  auto stageB = [&](int half, int t) {
    char* hb = lds + (long)(t & 1) * BUF + 32768 + half * 16384;
    const u16* g = BT + (tn + half * 128) * (long)K + (long)t * 64;
#pragma unroll
    for (int j = 0; j < 2; ++j) {
      const int idx = j * 512 + tid;
      const int r = idx >> 3;
      const int c16 = (idx & 7) ^ (r & 7);
      GLDS16(g + (long)r * K + c16 * 8, hb + idx * 16);
    }
  };

  stageA(0, 0); stageA(1, 0); stageB(0, 0); stageB(1, 0);
  stageB(0, 1); stageB(1, 1);
  asm volatile("s_waitcnt vmcnt(%0)" ::"n"(WST) : "memory");
  __builtin_amdgcn_s_barrier();

  f32x4 acc[8][NR];
#pragma unroll
  for (int m = 0; m < 8; ++m)
#pragma unroll
    for (int n = 0; n < NR; ++n) acc[m][n] = (f32x4){0.f, 0.f, 0.f, 0.f};

  const int lk = (lane >> 4) * 16;
  const int lr = lane & 15;

  for (int t = 0; t < NT; ++t) {
    const char* bp = lds + (long)(t & 1) * BUF;
    s16x8 bfr[NR][2];
#pragma unroll
    for (int p = 0; p < 4; ++p) {
      if (p == 0) {
#pragma unroll
        for (int ni = 0; ni < NR; ++ni) {
          const int brow = wc * (BN / 4) + ni * 16 + lr;
#pragma unroll
          for (int ks = 0; ks < 2; ++ks) {
            const int kb = (ks * 64 + lk) ^ ((brow & 7) << 4);
            bfr[ni][ks] = *(const s16x8*)(bp + 32768 + brow * 128 + kb);
          }
        }
      }
      s16x8 afr[2][2];
#pragma unroll
      for (int rI = 0; rI < 2; ++rI) {
        const int arow = wr * 128 + (2 * p + rI) * 16 + lr;
#pragma unroll
        for (int ks = 0; ks < 2; ++ks) {
          const int kb = (ks * 64 + lk) ^ ((arow & 7) << 4);
          afr[rI][ks] = *(const s16x8*)(bp + arow * 128 + kb);
        }
      }
      if (p == 0) { if (t + 1 < NT) stageA(0, t + 1); }
      else if (p == 1) { if (t + 1 < NT) stageA(1, t + 1); }
      else if (p == 2) { if (t + 2 < NT) stageB(0, t + 2); }
      else { if (t + 2 < NT) stageB(1, t + 2); }
      __builtin_amdgcn_s_barrier();
      __builtin_amdgcn_s_setprio(1);
#pragma unroll
      for (int rI = 0; rI < 2; ++rI)
#pragma unroll
        for (int ni = 0; ni < NR; ++ni)
#pragma unroll
          for (int ks = 0; ks < 2; ++ks)
            acc[2 * p + rI][ni] = mfma16(afr[rI][ks], bfr[ni][ks], acc[2 * p + rI][ni]);
      __builtin_amdgcn_s_setprio(0);
      if (p == 3) {
        if (t + 2 < NT) {
          asm volatile("s_waitcnt vmcnt(%0)" ::"n"(WST) : "memory");
        } else if (t + 1 < NT) {
          asm volatile("s_waitcnt vmcnt(0)" ::: "memory");
        }
      }
      __builtin_amdgcn_s_barrier();
    }
  }

  const long crow0 = tm + wr * 128 + ((lane >> 4) * 4);
  const long ccol0 = tn + wc * (BN / 4) + lr;
#pragma unroll
  for (int m = 0; m < 8; ++m)
#pragma unroll
    for (int n = 0; n < NR; ++n)
#pragma unroll
      for (int i = 0; i < 4; ++i) {
        const long row = crow0 + m * 16 + i;
        const long col = ccol0 + n * 16;
        const float v = acc[m][n][i] + bias[col];
        C[row * (long)ldc + col] = f2bf(fmaxf(v, 0.f));
      }
}

// ---------------- cooperative FFN2 (256x128 8-phase, +bf16 residual) + LN2
__global__ __launch_bounds__(512, 2) void ffn2_ln2(
    const u16* __restrict__ A, const u16* __restrict__ BT, u16* __restrict__ yb,
    const float* __restrict__ bias, const u16* __restrict__ Rb,
    const float* __restrict__ g2, const float* __restrict__ bb2,
    float* __restrict__ out) {
  extern __shared__ char lds[];
  constexpr int BN = 128, NR = 2, BUF = 32768 + BN * 128, WST = 2;
  const int K = DF_, N = D_, ldc = D_;
  const int tid = threadIdx.x;
  const int lane = tid & 63;
  const int w = tid >> 6;
  const int wr = w >> 2, wc = w & 3;
  const int total = gridDim.x;
  int bid = blockIdx.x;
  int s = ((total & 7) == 0) ? ((bid & 7) * (total >> 3) + (bid >> 3)) : bid;
  const int gn = N / BN;
  const long tm = (long)(s / gn) * 256;
  const long tn = (long)(s % gn) * BN;
  const int NT = K >> 6;

  auto stageA = [&](int half, int t) {
    char* hb = lds + (long)(t & 1) * BUF + half * 16384;
    const u16* g = A + (tm + half * 128) * (long)K + (long)t * 64;
#pragma unroll
    for (int j = 0; j < 2; ++j) {
      const int idx = j * 512 + tid;
      const int r = idx >> 3;
      const int c16 = (idx & 7) ^ (r & 7);
      GLDS16(g + (long)r * K + c16 * 8, hb + idx * 16);
    }
  };
  auto stageB = [&](int t) {
    char* hb = lds + (long)(t & 1) * BUF + 32768;
    const u16* g = BT + tn * (long)K + (long)t * 64;
#pragma unroll
    for (int j = 0; j < 2; ++j) {
      const int idx = j * 512 + tid;
      const int r = idx >> 3;
      const int c16 = (idx & 7) ^ (r & 7);
      GLDS16(g + (long)r * K + c16 * 8, hb + idx * 16);
    }
  };

  stageA(0, 0); stageA(1, 0); stageB(0); stageB(1);
  asm volatile("s_waitcnt vmcnt(%0)" ::"n"(WST) : "memory");
  __builtin_amdgcn_s_barrier();

  f32x4 acc[8][NR];
#pragma unroll
  for (int m = 0; m < 8; ++m)
#pragma unroll
    for (int n = 0; n < NR; ++n) acc[m][n] = (f32x4){0.f, 0.f, 0.f, 0.f};

  const int lk = (lane >> 4) * 16;
  const int lr = lane & 15;

  for (int t = 0; t < NT; ++t) {
    const char* bp = lds + (long)(t & 1) * BUF;
    s16x8 bfr[NR][2];
#pragma unroll
    for (int p = 0; p < 4; ++p) {
      if (p == 0) {
#pragma unroll
        for (int ni = 0; ni < NR; ++ni) {
          const int brow = wc * (BN / 4) + ni * 16 + lr;
#pragma unroll
          for (int ks = 0; ks < 2; ++ks) {
            const int kb = (ks * 64 + lk) ^ ((brow & 7) << 4);
            bfr[ni][ks] = *(const s16x8*)(bp + 32768 + brow * 128 + kb);
          }
        }
      }
      s16x8 afr[2][2];
#pragma unroll
      for (int rI = 0; rI < 2; ++rI) {
        const int arow = wr * 128 + (2 * p + rI) * 16 + lr;
#pragma unroll
        for (int ks = 0; ks < 2; ++ks) {
          const int kb = (ks * 64 + lk) ^ ((arow & 7) << 4);
          afr[rI][ks] = *(const s16x8*)(bp + arow * 128 + kb);
        }
      }
      if (p == 0) { if (t + 1 < NT) stageA(0, t + 1); }
      else if (p == 1) { if (t + 1 < NT) stageA(1, t + 1); }
      else if (p == 2) { if (t + 2 < NT) stageB(t + 2); }
      __builtin_amdgcn_s_barrier();
      __builtin_amdgcn_s_setprio(1);
#pragma unroll
      for (int rI = 0; rI < 2; ++rI)
#pragma unroll
        for (int ni = 0; ni < NR; ++ni)
#pragma unroll
          for (int ks = 0; ks < 2; ++ks)
            acc[2 * p + rI][ni] = mfma16(afr[rI][ks], bfr[ni][ks], acc[2 * p + rI][ni]);
      __builtin_amdgcn_s_setprio(0);
      if (p == 3) {
        if (t + 2 < NT) {
          asm volatile("s_waitcnt vmcnt(%0)" ::"n"(WST) : "memory");
        } else if (t + 1 < NT) {
          asm volatile("s_waitcnt vmcnt(0)" ::: "memory");
        }
      }
      __builtin_amdgcn_s_barrier();
    }
  }

  {
    const long crow0 = tm + wr * 128 + ((lane >> 4) * 4);
    const long ccol0 = tn + wc * (BN / 4) + lr;
#pragma unroll
    for (int m = 0; m < 8; ++m)
#pragma unroll
      for (int n = 0; n < NR; ++n)
#pragma unroll
        for (int i = 0; i < 4; ++i) {
          const long row = crow0 + m * 16 + i;
          const long col = ccol0 + n * 16;
          const float v = acc[m][n][i] + bias[col];
          const float r = bf2f(Rb[row * (long)ldc + col]);
          yb[row * (long)ldc + col] = f2bf(v + r);
        }
  }

  cg::this_grid().sync();

  // LN2: 32 rows per block, 2 rows per iter (512 threads)
  float* ssq = (float*)lds;  // 16 floats scratch
  const int tsub = tid & 255;
  const int grp = tid >> 8;
  const int wvg = (tid >> 6) & 3;
  for (int it = 0; it < 16; ++it) {
    const long row = (long)blockIdx.x * 32 + it * 2 + grp;
    const uint2 pk = *(const uint2*)(yb + row * D_ + tsub * 4);
    float4 v;
    v.x = __uint_as_float((pk.x & 0xFFFFu) << 16);
    v.y = __uint_as_float(pk.x & 0xFFFF0000u);
    v.z = __uint_as_float((pk.y & 0xFFFFu) << 16);
    v.w = __uint_as_float(pk.y & 0xFFFF0000u);
    float sm = v.x + v.y + v.z + v.w;
    float qm = v.x * v.x + v.y * v.y + v.z * v.z + v.w * v.w;
#pragma unroll
    for (int d = 1; d < 64; d <<= 1) { sm += __shfl_xor(sm, d); qm += __shfl_xor(qm, d); }
    if ((tid & 63) == 0) { ssq[grp * 4 + wvg] = sm; ssq[8 + grp * 4 + wvg] = qm; }
    __syncthreads();
    sm = ssq[grp * 4 + 0] + ssq[grp * 4 + 1] + ssq[grp * 4 + 2] + ssq[grp * 4 + 3];
    qm = ssq[8 + grp * 4 + 0] + ssq[8 + grp * 4 + 1] + ssq[8 + grp * 4 + 2] +
         ssq[8 + grp * 4 + 3];
    const float mu = sm * (1.f / D_);
    const float var = qm * (1.f / D_) - mu * mu;
    const float rs = rsqrtf(var + 1e-5f);
    const float4 gv = ((const float4*)g2)[tsub];
    const float4 bv = ((const float4*)bb2)[tsub];
    float4 o;
    o.x = (v.x - mu) * rs * gv.x + bv.x;
    o.y = (v.y - mu) * rs * gv.y + bv.y;
    o.z = (v.z - mu) * rs * gv.z + bv.z;
    o.w = (v.w - mu) * rs * gv.w + bv.w;
    ((float4*)(out + row * D_))[tsub] = o;
    __syncthreads();
  }
}

extern "C" void kernel_launch(void* const* d_in, const int* in_sizes, int n_in,
                              void* d_out, int out_size, void* d_ws, size_t ws_size,
                              hipStream_t stream) {
  (void)in_sizes; (void)n_in; (void)out_size; (void)ws_size;
  const float* src = (const float*)d_in[0];
  const float* sf = (const float*)d_in[1];
  const int* mask = (const int*)d_in[2];
  const float* qw = (const float*)d_in[3];
  const float* qb = (const float*)d_in[4];
  const float* kw = (const float*)d_in[5];
  const float* kb = (const float*)d_in[6];
  const float* vw = (const float*)d_in[7];
  const float* vb = (const float*)d_in[8];
  const float* b1w = (const float*)d_in[9];
  const float* b1b = (const float*)d_in[10];
  const float* b2w = (const float*)d_in[11];
  const float* b2b = (const float*)d_in[12];
  const float* ow = (const float*)d_in[13];
  const float* ob = (const float*)d_in[14];
  const float* ln1g = (const float*)d_in[15];
  const float* ln1b = (const float*)d_in[16];
  const float* ln2g = (const float*)d_in[17];
  const float* ln2b = (const float*)d_in[18];
  const float* w1 = (const float*)d_in[19];
  const float* bf1 = (const float*)d_in[20];
  const float* w2 = (const float*)d_in[21];
  const float* bf2 = (const float*)d_in[22];
  float* out = (float*)d_out;

  char* ws = (char*)d_ws;
  size_t off = 0;
  auto alloc = [&](size_t bytes) {
    void* p = ws + off;
    off += (bytes + 255) & ~(size_t)255;
    return p;
  };
  u16* qwT = (u16*)alloc((size_t)H_ * DQ_ * D_ * 2);
  u16* kwT = (u16*)alloc((size_t)H_ * DQ_ * D_ * 2);
  u16* vwT = (u16*)alloc((size_t)H_ * DQ_ * D_ * 2);
  u16* owT = (u16*)alloc((size_t)D_ * D_ * 2);
  u16* w1T = (u16*)alloc((size_t)DF_ * D_ * 2);
  u16* w2T = (u16*)alloc((size_t)D_ * DF_ * 2);
  u16* src0b = (u16*)alloc((size_t)L_ * D_ * 2);
  u16* q0 = (u16*)alloc((size_t)H_ * L_ * DQ_ * 2);
  u16* k0 = (u16*)alloc((size_t)H_ * L_ * DQ_ * 2);
  u16* v0T = (u16*)alloc((size_t)H_ * DQ_ * L_ * 2);
  float* nzv = (float*)alloc((size_t)H_ * DM_ * 4);
  int* nzi = (int*)alloc((size_t)H_ * DM_ * 4);
  int* nzcnt = (int*)alloc(256);
  float* biasb = (float*)alloc((size_t)H_ * L_ * L_ * 4);
  u16* hidden = (u16*)alloc((size_t)L_ * H_ * DQ_ * 2);
  float* attnvec = (float*)alloc((size_t)L_ * D_ * 4);
  u16* xb = (u16*)alloc((size_t)B_ * L_ * D_ * 2);
  u16* ffnh = (u16*)alloc((size_t)B_ * L_ * DF_ * 2);
  u16* yb = (u16*)alloc((size_t)B_ * L_ * D_ * 2);
  int* qhead = (int*)alloc(256);

  hipFuncSetAttribute((const void*)gemm8p_ffn1,
                      hipFuncAttributeMaxDynamicSharedMemorySize, 131072);
  hipFuncSetAttribute((const void*)ffn2_ln2,
                      hipFuncAttributeMaxDynamicSharedMemorySize, 98304);

  // K1: all weight transposes + src conv + hid + queue reset
  prep<<<dim3(12552), dim3(256), 0, stream>>>(
      qw, kw, vw, ow, w1, w2, src, sf, b1w, b1b, qwT, kwT, vwT, owT, w1T, w2T,
      src0b, nzv, nzi, nzcnt, qhead);

  // K2: cooperative {gemv+qkv | attn | proj | ln1}
  MidArgs ma;
  ma.nzv = nzv; ma.nzi = nzi; ma.nzcnt = nzcnt;
  ma.b2w = b2w; ma.b2b = b2b; ma.biasb = biasb;
  ma.src0b = src0b; ma.qwT = qwT; ma.kwT = kwT; ma.vwT = vwT;
  ma.qb = qb; ma.kb = kb; ma.vb = vb;
  ma.q0 = q0; ma.k0 = k0; ma.v0T = v0T;
  ma.mask = mask; ma.hidden = hidden;
  ma.owT = owT; ma.ob = ob; ma.attnvec = attnvec;
  ma.src = src; ma.ln1g = ln1g; ma.ln1b = ln1b; ma.xb = xb;
  ma.qhead = qhead;
  void* kpm[] = {&ma};
  hipLaunchCooperativeKernel((void*)mid_kernel, dim3(256), dim3(256), kpm, 0,
                             stream);

  // K3: FFN1 relu(x @ w1 + bf1) -> ffnh bf16
  gemm8p_ffn1<<<dim3(512), dim3(512), 131072, stream>>>(xb, w1T, ffnh, bf1);

  // K4: cooperative FFN2 (+residual) + LN2 -> d_out
  const u16* aP = ffnh; const u16* btP = w2T; u16* ybP = yb;
  const float* biP = bf2; const u16* rP = xb;
  const float* gP = ln2g; const float* bbP = ln2b; float* oP = out;
  void* kp2[] = {&aP, &btP, &ybP, &biP, &rP, &gP, &bbP, &oP};
  hipLaunchCooperativeKernel((void*)ffn2_ln2, dim3(256), dim3(512), kp2, 98304,
                             stream);
}

// Round 5
// 356.536 us; speedup vs baseline: 1.3260x; 1.3260x over previous
//
#include <hip/hip_runtime.h>

typedef unsigned short u16;
typedef short s16x8 __attribute__((ext_vector_type(8)));
typedef u16 u16x4 __attribute__((ext_vector_type(4)));
typedef float f32x4 __attribute__((ext_vector_type(4)));

#define B_ 32
#define L_ 256
#define D_ 1024
#define H_ 8
#define DQ_ 128
#define DS_ 64
#define DM_ 256
#define DF_ 4096

__device__ __forceinline__ u16 f2bf(float f) {
  unsigned u = __float_as_uint(f);
  unsigned r = (u + 0x7FFFu + ((u >> 16) & 1u)) >> 16;
  return (u16)r;
}
__device__ __forceinline__ float bf2f(u16 x) {
  return __uint_as_float(((unsigned)x) << 16);
}

__device__ __forceinline__ f32x4 mfma16(s16x8 a, s16x8 b, f32x4 c) {
  return __builtin_amdgcn_mfma_f32_16x16x32_bf16(a, b, c, 0, 0, 0);
}

#define GLDS16(g, l)                                                        \
  __builtin_amdgcn_global_load_lds(                                         \
      (__attribute__((address_space(1))) const void*)(g),                   \
      (__attribute__((address_space(3))) void*)(l), 16, 0, 0)

// ---------------- 32x32 transpose+convert tile helper
__device__ __forceinline__ void tile_tr(const float* __restrict__ ip,
                                        u16* __restrict__ op, int K, int N,
                                        int bx, int by, float (*t)[33], int tid) {
  const int tx = tid & 31, ty = tid >> 5;
  const long n0 = (long)bx * 32, k0 = (long)by * 32;
#pragma unroll
  for (int i = 0; i < 4; ++i)
    t[ty + i * 8][tx] = ip[(k0 + ty + i * 8) * (long)N + n0 + tx];
  __syncthreads();
#pragma unroll
  for (int i = 0; i < 4; ++i)
    op[(n0 + ty + i * 8) * (long)K + k0 + tx] = f2bf(t[tx][ty + i * 8]);
}

// ---------------- prep: qkv transposes + src b0 conversion + hid
// grid: [0,3072) qkvT | [3072,3328) conv src b0 | [3328,3336) hid
__global__ __launch_bounds__(256) void prep(
    const float* __restrict__ qw, const float* __restrict__ kw,
    const float* __restrict__ vw, const float* __restrict__ src,
    const float* __restrict__ sf, const float* __restrict__ b1w,
    const float* __restrict__ b1b, u16* __restrict__ qwT, u16* __restrict__ kwT,
    u16* __restrict__ vwT, u16* __restrict__ src0b, float* __restrict__ nzv,
    int* __restrict__ nzi, int* __restrict__ nzcnt) {
  const int b = blockIdx.x;
  const int tid = threadIdx.x;
  __shared__ float t[32][33];
  __shared__ float s_sf[DS_];
  __shared__ int wcnt[4];
  if (b < 3072) {
    const int z = b >> 7, rem = b & 127;
    const int sel = z >> 3, h = z & 7;
    const float* ip = (sel == 0 ? qw : (sel == 1 ? kw : vw)) + (long)h * D_ * DQ_;
    u16* op = (sel == 0 ? qwT : (sel == 1 ? kwT : vwT)) + (long)h * DQ_ * D_;
    tile_tr(ip, op, D_, DQ_, rem & 3, rem >> 2, t, tid);
  } else if (b < 3328) {
    const int rem = b - 3072;
    const int i = (rem * 256 + tid) * 4;
    float4 v = *(const float4*)(src + i);
    u16x4 o = {f2bf(v.x), f2bf(v.y), f2bf(v.z), f2bf(v.w)};
    *(u16x4*)(src0b + i) = o;
  } else {
    const int h = b - 3328;
    if (tid < DS_) s_sf[tid] = sf[tid];
    __syncthreads();
    float a = b1b[h * DM_ + tid];
    const float* wp = b1w + (long)h * DS_ * DM_ + tid;
#pragma unroll 8
    for (int s = 0; s < DS_; ++s) a += s_sf[s] * wp[s * DM_];
    a = fmaxf(a, 0.f);
    const unsigned long long bal = __ballot(a > 0.f);
    const int lane = tid & 63, wv = tid >> 6;
    const int pc = __popcll(bal);
    if (lane == 0) wcnt[wv] = pc;
    __syncthreads();
    int base = 0;
    for (int i = 0; i < wv; ++i) base += wcnt[i];
    const int pos = base + __popcll(bal & ((1ull << lane) - 1ull));
    if (a > 0.f) { nzv[h * DM_ + pos] = a; nzi[h * DM_ + pos] = tid; }
    if (tid == 255) nzcnt[h] = base + pc;
  }
}

// ---------------- phase2: gemv [0,512) | qkv proj [512,560) |
//   owT [560,1584) | w1T [1584,5680) | w2T [5680,9776)
__global__ __launch_bounds__(256) void phase2(
    const float* __restrict__ nzv, const int* __restrict__ nzi,
    const int* __restrict__ nzcnt, const float* __restrict__ b2w,
    const float* __restrict__ b2b, float* __restrict__ biasb,
    const u16* __restrict__ src0b, const u16* __restrict__ qwT,
    const u16* __restrict__ kwT, const u16* __restrict__ vwT,
    const float* __restrict__ qb, const float* __restrict__ kb,
    const float* __restrict__ vb, u16* __restrict__ q0, u16* __restrict__ k0,
    u16* __restrict__ v0T, const float* __restrict__ ow,
    const float* __restrict__ w1, const float* __restrict__ w2,
    u16* __restrict__ owT, u16* __restrict__ w1T, u16* __restrict__ w2T) {
  const int b = blockIdx.x;
  const int tid = threadIdx.x;
  __shared__ float sv[DM_];
  __shared__ int si[DM_];
  __shared__ u16 smA[128 * 32];
  __shared__ u16 smB[128 * 32];
  __shared__ float t[32][33];
  if (b < 512) {
    const int h = b >> 6;
    const int n0 = (b & 63) << 10;
    const int nnz = nzcnt[h];
    if (tid < DM_) { sv[tid] = nzv[h * DM_ + tid]; si[tid] = nzi[h * DM_ + tid]; }
    __syncthreads();
    const float* wb = b2w + (long)h * DM_ * 65536 + n0 + tid * 4;
    float4 acc = {0.f, 0.f, 0.f, 0.f};
    int j = 0;
    for (; j + 4 <= nnz; j += 4) {
      const float4 a0 = *(const float4*)(wb + (long)si[j] * 65536);
      const float4 a1 = *(const float4*)(wb + (long)si[j + 1] * 65536);
      const float4 a2 = *(const float4*)(wb + (long)si[j + 2] * 65536);
      const float4 a3 = *(const float4*)(wb + (long)si[j + 3] * 65536);
      const float v0 = sv[j], v1 = sv[j + 1], v2 = sv[j + 2], v3 = sv[j + 3];
      acc.x += v0 * a0.x + v1 * a1.x + v2 * a2.x + v3 * a3.x;
      acc.y += v0 * a0.y + v1 * a1.y + v2 * a2.y + v3 * a3.y;
      acc.z += v0 * a0.z + v1 * a1.z + v2 * a2.z + v3 * a3.z;
      acc.w += v0 * a0.w + v1 * a1.w + v2 * a2.w + v3 * a3.w;
    }
    for (; j < nnz; ++j) {
      const float4 a0 = *(const float4*)(wb + (long)si[j] * 65536);
      const float v0 = sv[j];
      acc.x += v0 * a0.x; acc.y += v0 * a0.y; acc.z += v0 * a0.z; acc.w += v0 * a0.w;
    }
    const float4 bb = *(const float4*)(b2b + (long)h * 65536 + n0 + tid * 4);
    float4 o = {acc.x + bb.x, acc.y + bb.y, acc.z + bb.z, acc.w + bb.w};
    *(float4*)(biasb + (long)h * 65536 + n0 + tid * 4) = o;
  } else if (b < 560) {
    const int r = b - 512;
    const int z = r >> 1, sel = z >> 3, h = z & 7;
    const long tm = (long)(r & 1) * 128;
    const int K = D_;
    const u16* BT = (sel == 0 ? qwT : (sel == 1 ? kwT : vwT)) + (long)h * DQ_ * D_;
    const float* bias = (sel == 0 ? qb : (sel == 1 ? kb : vb)) + h * DQ_;
    const int lane = tid & 63;
    const int wv = tid >> 6;
    const int wr = wv >> 1, wc = wv & 1;
    const u16* ga = src0b + (tm + (tid >> 2)) * (long)K + (tid & 3) * 8;
    const u16* gb = BT + (long)(tid >> 2) * K + (tid & 3) * 8;
    const long rstep = 64L * K;
    u16* la = &smA[tid * 8];
    u16* lb = &smB[tid * 8];
    f32x4 acc[4][4];
#pragma unroll
    for (int m = 0; m < 4; ++m)
#pragma unroll
      for (int n = 0; n < 4; ++n) acc[m][n] = (f32x4){0.f, 0.f, 0.f, 0.f};
    for (int k0_ = 0; k0_ < K; k0_ += 32) {
      GLDS16(ga + k0_, la);
      GLDS16(ga + rstep + k0_, la + 64 * 32);
      GLDS16(gb + k0_, lb);
      GLDS16(gb + rstep + k0_, lb + 64 * 32);
      __syncthreads();
      s16x8 af[4], bf[4];
      const int ka = (lane >> 4) * 8;
      const int ra = wr * 64 + (lane & 15);
      const int rb = wc * 64 + (lane & 15);
#pragma unroll
      for (int m = 0; m < 4; ++m) af[m] = *(const s16x8*)&smA[(ra + m * 16) * 32 + ka];
#pragma unroll
      for (int n = 0; n < 4; ++n) bf[n] = *(const s16x8*)&smB[(rb + n * 16) * 32 + ka];
#pragma unroll
      for (int m = 0; m < 4; ++m)
#pragma unroll
        for (int n = 0; n < 4; ++n) acc[m][n] = mfma16(af[m], bf[n], acc[m][n]);
      __syncthreads();
    }
    const long crow0 = tm + wr * 64 + ((lane >> 4) * 4);
    const long ccol0 = wc * 64 + (lane & 15);
#pragma unroll
    for (int m = 0; m < 4; ++m)
#pragma unroll
      for (int n = 0; n < 4; ++n)
#pragma unroll
        for (int i = 0; i < 4; ++i) {
          const long row = crow0 + m * 16 + i;
          const long col = ccol0 + n * 16;
          const float v = acc[m][n][i] + bias[col];
          if (sel < 2) {
            u16* o = (sel == 0 ? q0 : k0) + (long)h * L_ * DQ_;
            o[row * DQ_ + col] = f2bf(v);
          } else {
            v0T[(long)h * DQ_ * L_ + col * L_ + row] = f2bf(v);
          }
        }
  } else if (b < 1584) {
    const int rem = b - 560;
    tile_tr(ow, owT, D_, D_, rem & 31, rem >> 5, t, tid);
  } else if (b < 5680) {
    const int rem = b - 1584;
    tile_tr(w1, w1T, D_, DF_, rem & 127, rem >> 7, t, tid);
  } else {
    const int rem = b - 5680;
    tile_tr(w2, w2T, DF_, D_, rem & 31, rem >> 5, t, tid);
  }
}

// ---------------- fused attention + out-projection for batch 0
// 16 blocks x 512 thr (8 waves). Block j: rows [16j,16j+16).
// Wave h: head-h attention -> swizzled LDS hid tile; barrier; all waves proj.
__global__ __launch_bounds__(512) void attnproj(
    const u16* __restrict__ q0, const u16* __restrict__ k0,
    const u16* __restrict__ v0T, const float* __restrict__ biasb,
    const int* __restrict__ mask, const u16* __restrict__ owT,
    const float* __restrict__ ob, float* __restrict__ attnvec) {
  extern __shared__ char alds[];  // [0,64K) per-wave P bufs, [64K,96K) hid tile
  const int tid = threadIdx.x;
  const int h = tid >> 6;       // wave = head
  const int lane = tid & 63;
  const int lg = lane >> 4;
  const int ll = lane & 15;
  const int r0 = blockIdx.x * 16;

  // ---- phase A: scores + softmax + bias for head h, rows [r0, r0+16)
  const u16* q = q0 + (long)h * L_ * DQ_;
  const u16* k = k0 + (long)h * L_ * DQ_;
  s16x8 aq[4];
#pragma unroll
  for (int kk = 0; kk < 4; ++kk)
    aq[kk] = *(const s16x8*)(q + (long)(r0 + ll) * DQ_ + kk * 32 + lg * 8);
  float sc[16][4];
  const float scale = 0.08838834764831845f;  // 1/sqrt(128)
#pragma unroll
  for (int t = 0; t < 16; ++t) {
    f32x4 a = {0.f, 0.f, 0.f, 0.f};
#pragma unroll
    for (int kk = 0; kk < 4; ++kk) {
      s16x8 bf = *(const s16x8*)(k + (long)(t * 16 + ll) * DQ_ + kk * 32 + lg * 8);
      a = mfma16(aq[kk], bf, a);
    }
#pragma unroll
    for (int i = 0; i < 4; ++i) {
      const int row = r0 + lg * 4 + i;
      const int col = t * 16 + ll;
      float s = a[i] * scale;
      if (mask[row * L_ + col] != 0) s = 1e-9f;
      sc[t][i] = s;
    }
  }
#pragma unroll
  for (int i = 0; i < 4; ++i) {
    float mx = sc[0][i];
#pragma unroll
    for (int t = 1; t < 16; ++t) mx = fmaxf(mx, sc[t][i]);
#pragma unroll
    for (int d = 1; d < 16; d <<= 1) mx = fmaxf(mx, __shfl_xor(mx, d));
    float sum = 0.f;
#pragma unroll
    for (int t = 0; t < 16; ++t) {
      const float e = __expf(sc[t][i] - mx);
      sc[t][i] = e;
      sum += e;
    }
#pragma unroll
    for (int d = 1; d < 16; d <<= 1) sum += __shfl_xor(sum, d);
    const float inv = 1.f / sum;
    const int row = r0 + lg * 4 + i;
#pragma unroll
    for (int t = 0; t < 16; ++t)
      sc[t][i] = sc[t][i] * inv + biasb[(long)h * 65536 + (long)row * 256 + t * 16 + ll];
  }
  // write P (bf16) into this wave's swizzled LDS region [16][256]
  char* pbuf = alds + h * 8192;
#pragma unroll
  for (int t = 0; t < 16; ++t)
#pragma unroll
    for (int i = 0; i < 4; ++i) {
      const int lr = lg * 4 + i;
      const int cb = (t * 16 + ll) * 2;
      *(u16*)(pbuf + lr * 512 + (cb ^ ((lr & 7) << 4))) = f2bf(sc[t][i]);
    }
  // ---- phase B: PV -> hid tile (within-wave LDS dep, compiler waits lgkmcnt)
  const u16* v = v0T + (long)h * DQ_ * L_;
  char* hidb = alds + 65536;
#pragma unroll
  for (int kk = 0; kk < 8; ++kk) {
    // (kept in regs via unrolled loop; af read per n-loop below instead)
  }
  s16x8 paf[8];
#pragma unroll
  for (int kk = 0; kk < 8; ++kk)
    paf[kk] = *(const s16x8*)(pbuf + ll * 512 + ((kk * 64 + lg * 16) ^ ((ll & 7) << 4)));
#pragma unroll
  for (int n = 0; n < 8; ++n) {
    f32x4 a = {0.f, 0.f, 0.f, 0.f};
#pragma unroll
    for (int kk = 0; kk < 8; ++kk) {
      s16x8 bf = *(const s16x8*)(v + (long)(n * 16 + ll) * 256 + kk * 32 + lg * 8);
      a = mfma16(paf[kk], bf, a);
    }
#pragma unroll
    for (int i = 0; i < 4; ++i) {
      const int lr = lg * 4 + i;
      const int cb = (h * 128 + n * 16 + ll) * 2;
      *(u16*)(hidb + lr * 2048 + (cb ^ ((lr & 7) << 4))) = f2bf(a[i]);
    }
  }
  __syncthreads();
  // ---- phase C: proj. wave h handles cols [128h, 128h+128).
  f32x4 acc[8];
#pragma unroll
  for (int f = 0; f < 8; ++f) acc[f] = (f32x4){0.f, 0.f, 0.f, 0.f};
#pragma unroll 2
  for (int k0_ = 0; k0_ < 1024; k0_ += 32) {
    const s16x8 af = *(const s16x8*)(hidb + ll * 2048 + ((k0_ * 2 + lg * 16) ^ ((ll & 7) << 4)));
#pragma unroll
    for (int f = 0; f < 8; ++f) {
      const s16x8 bf = *(const s16x8*)(owT + (long)(h * 128 + f * 16 + ll) * 1024 + k0_ + lg * 8);
      acc[f] = mfma16(af, bf, acc[f]);
    }
  }
#pragma unroll
  for (int f = 0; f < 8; ++f)
#pragma unroll
    for (int i = 0; i < 4; ++i) {
      const int row = r0 + lg * 4 + i;
      const int col = h * 128 + f * 16 + ll;
      attnvec[(long)row * D_ + col] = acc[f][i] + ob[col];
    }
}

// ---------------- 8-phase 256xBN deep-pipelined GEMM (T1+T2+T4+T5)
// EPI: 1 = bf16 out relu(+bias); 2 = bf16 out +bias +bf16 residual
template <int BN, int EPI>
__global__ __launch_bounds__(512, 2) void gemm8p(
    const u16* __restrict__ A, const u16* __restrict__ BT, void* __restrict__ Cv,
    const float* __restrict__ bias, const void* __restrict__ R, int M, int N,
    int K, int ldc) {
  extern __shared__ char lds[];
  constexpr int NR = BN / 64;
  constexpr int NHB = BN / 128;
  constexpr int BUF = 32768 + BN * 128;
  constexpr int WST = (NHB == 2) ? 4 : 2;
  const int tid = threadIdx.x;
  const int lane = tid & 63;
  const int w = tid >> 6;
  const int wr = w >> 2, wc = w & 3;

  const int total = gridDim.x;
  int bid = blockIdx.x;
  int s = ((total & 7) == 0) ? ((bid & 7) * (total >> 3) + (bid >> 3)) : bid;
  const int gn = N / BN;
  const long tm = (long)(s / gn) * 256;
  const long tn = (long)(s % gn) * BN;
  const int NT = K >> 6;

  auto stageA = [&](int half, int t) {
    char* hb = lds + (long)(t & 1) * BUF + half * 16384;
    const u16* g = A + (tm + half * 128) * (long)K + (long)t * 64;
#pragma unroll
    for (int j = 0; j < 2; ++j) {
      const int idx = j * 512 + tid;
      const int r = idx >> 3;
      const int c16 = (idx & 7) ^ (r & 7);
      GLDS16(g + (long)r * K + c16 * 8, hb + idx * 16);
    }
  };
  auto stageB = [&](int half, int t) {
    char* hb = lds + (long)(t & 1) * BUF + 32768 + half * 16384;
    const u16* g = BT + (tn + half * 128) * (long)K + (long)t * 64;
#pragma unroll
    for (int j = 0; j < 2; ++j) {
      const int idx = j * 512 + tid;
      const int r = idx >> 3;
      const int c16 = (idx & 7) ^ (r & 7);
      GLDS16(g + (long)r * K + c16 * 8, hb + idx * 16);
    }
  };

  stageA(0, 0);
  stageA(1, 0);
  stageB(0, 0);
  if (NHB == 2) stageB(1, 0);
  stageB(0, 1);
  if (NHB == 2) stageB(1, 1);
  asm volatile("s_waitcnt vmcnt(%0)" ::"n"(WST) : "memory");
  __builtin_amdgcn_s_barrier();

  f32x4 acc[8][NR];
#pragma unroll
  for (int m = 0; m < 8; ++m)
#pragma unroll
    for (int n = 0; n < NR; ++n) acc[m][n] = (f32x4){0.f, 0.f, 0.f, 0.f};

  const int lk = (lane >> 4) * 16;
  const int lr = lane & 15;

  for (int t = 0; t < NT; ++t) {
    const char* bp = lds + (long)(t & 1) * BUF;
    s16x8 bfr[NR][2];
#pragma unroll
    for (int p = 0; p < 4; ++p) {
      if (p == 0) {
#pragma unroll
        for (int ni = 0; ni < NR; ++ni) {
          const int brow = wc * (BN / 4) + ni * 16 + lr;
#pragma unroll
          for (int ks = 0; ks < 2; ++ks) {
            const int kb = (ks * 64 + lk) ^ ((brow & 7) << 4);
            bfr[ni][ks] = *(const s16x8*)(bp + 32768 + brow * 128 + kb);
          }
        }
      }
      s16x8 afr[2][2];
#pragma unroll
      for (int rI = 0; rI < 2; ++rI) {
        const int arow = wr * 128 + (2 * p + rI) * 16 + lr;
#pragma unroll
        for (int ks = 0; ks < 2; ++ks) {
          const int kb = (ks * 64 + lk) ^ ((arow & 7) << 4);
          afr[rI][ks] = *(const s16x8*)(bp + arow * 128 + kb);
        }
      }
      if (p == 0) { if (t + 1 < NT) stageA(0, t + 1); }
      else if (p == 1) { if (t + 1 < NT) stageA(1, t + 1); }
      else if (p == 2) { if (t + 2 < NT) stageB(0, t + 2); }
      else { if (NHB == 2 && t + 2 < NT) stageB(1, t + 2); }
      __builtin_amdgcn_s_barrier();
      __builtin_amdgcn_s_setprio(1);
#pragma unroll
      for (int rI = 0; rI < 2; ++rI)
#pragma unroll
        for (int ni = 0; ni < NR; ++ni)
#pragma unroll
          for (int ks = 0; ks < 2; ++ks)
            acc[2 * p + rI][ni] = mfma16(afr[rI][ks], bfr[ni][ks], acc[2 * p + rI][ni]);
      __builtin_amdgcn_s_setprio(0);
      if (p == 3) {
        if (t + 2 < NT) {
          asm volatile("s_waitcnt vmcnt(%0)" ::"n"(WST) : "memory");
        } else if (t + 1 < NT) {
          asm volatile("s_waitcnt vmcnt(0)" ::: "memory");
        }
      }
      __builtin_amdgcn_s_barrier();
    }
  }

  const long crow0 = tm + wr * 128 + ((lane >> 4) * 4);
  const long ccol0 = tn + wc * (BN / 4) + lr;
#pragma unroll
  for (int m = 0; m < 8; ++m) {
#pragma unroll
    for (int n = 0; n < NR; ++n) {
#pragma unroll
      for (int i = 0; i < 4; ++i) {
        const long row = crow0 + m * 16 + i;
        const long col = ccol0 + n * 16;
        const float v = acc[m][n][i] + bias[col];
        if constexpr (EPI == 1) {
          ((u16*)Cv)[row * (long)ldc + col] = f2bf(fmaxf(v, 0.f));
        } else {
          const float r = bf2f(((const u16*)R)[row * (long)ldc + col]);
          ((u16*)Cv)[row * (long)ldc + col] = f2bf(v + r);
        }
      }
    }
  }
}

// ---------------- layernorm over D=1024
// MODE 0: in f32 + add f32 (attn row, row%L), out bf16
// MODE 1: in bf16, out f32
template <int MODE>
__global__ __launch_bounds__(256) void ln_kernel(
    const void* __restrict__ in0v, const float* __restrict__ add1,
    const float* __restrict__ g, const float* __restrict__ bb,
    void* __restrict__ outv) {
  const int tid = threadIdx.x;
  const long row = blockIdx.x;
  float4 v;
  if constexpr (MODE == 0) {
    v = ((const float4*)((const float*)in0v + row * D_))[tid];
    const float4 u = ((const float4*)(add1 + (row & (L_ - 1)) * D_))[tid];
    v.x += u.x; v.y += u.y; v.z += u.z; v.w += u.w;
  } else {
    const uint2 pk = *(const uint2*)((const u16*)in0v + row * D_ + tid * 4);
    v.x = __uint_as_float((pk.x & 0xFFFFu) << 16);
    v.y = __uint_as_float(pk.x & 0xFFFF0000u);
    v.z = __uint_as_float((pk.y & 0xFFFFu) << 16);
    v.w = __uint_as_float(pk.y & 0xFFFF0000u);
  }
  float s = v.x + v.y + v.z + v.w;
  float q = v.x * v.x + v.y * v.y + v.z * v.z + v.w * v.w;
#pragma unroll
  for (int d = 1; d < 64; d <<= 1) { s += __shfl_xor(s, d); q += __shfl_xor(q, d); }
  __shared__ float ss[4], sq[4];
  const int wv = tid >> 6;
  if ((tid & 63) == 0) { ss[wv] = s; sq[wv] = q; }
  __syncthreads();
  s = ss[0] + ss[1] + ss[2] + ss[3];
  q = sq[0] + sq[1] + sq[2] + sq[3];
  const float mu = s * (1.f / D_);
  const float var = q * (1.f / D_) - mu * mu;
  const float rs = rsqrtf(var + 1e-5f);
  const float4 gv = ((const float4*)g)[tid];
  const float4 bv = ((const float4*)bb)[tid];
  float4 o;
  o.x = (v.x - mu) * rs * gv.x + bv.x;
  o.y = (v.y - mu) * rs * gv.y + bv.y;
  o.z = (v.z - mu) * rs * gv.z + bv.z;
  o.w = (v.w - mu) * rs * gv.w + bv.w;
  if constexpr (MODE == 0) {
    uint2 pk;
    pk.x = (unsigned)f2bf(o.x) | ((unsigned)f2bf(o.y) << 16);
    pk.y = (unsigned)f2bf(o.z) | ((unsigned)f2bf(o.w) << 16);
    *(uint2*)((u16*)outv + row * D_ + tid * 4) = pk;
  } else {
    ((float4*)((float*)outv + row * D_))[tid] = o;
  }
}

extern "C" void kernel_launch(void* const* d_in, const int* in_sizes, int n_in,
                              void* d_out, int out_size, void* d_ws, size_t ws_size,
                              hipStream_t stream) {
  (void)in_sizes; (void)n_in; (void)out_size; (void)ws_size;
  const float* src = (const float*)d_in[0];
  const float* sf = (const float*)d_in[1];
  const int* mask = (const int*)d_in[2];
  const float* qw = (const float*)d_in[3];
  const float* qb = (const float*)d_in[4];
  const float* kw = (const float*)d_in[5];
  const float* kb = (const float*)d_in[6];
  const float* vw = (const float*)d_in[7];
  const float* vb = (const float*)d_in[8];
  const float* b1w = (const float*)d_in[9];
  const float* b1b = (const float*)d_in[10];
  const float* b2w = (const float*)d_in[11];
  const float* b2b = (const float*)d_in[12];
  const float* ow = (const float*)d_in[13];
  const float* ob = (const float*)d_in[14];
  const float* ln1g = (const float*)d_in[15];
  const float* ln1b = (const float*)d_in[16];
  const float* ln2g = (const float*)d_in[17];
  const float* ln2b = (const float*)d_in[18];
  const float* w1 = (const float*)d_in[19];
  const float* bf1 = (const float*)d_in[20];
  const float* w2 = (const float*)d_in[21];
  const float* bf2 = (const float*)d_in[22];
  float* out = (float*)d_out;

  char* ws = (char*)d_ws;
  size_t off = 0;
  auto alloc = [&](size_t bytes) {
    void* p = ws + off;
    off += (bytes + 255) & ~(size_t)255;
    return p;
  };
  u16* qwT = (u16*)alloc((size_t)H_ * DQ_ * D_ * 2);
  u16* kwT = (u16*)alloc((size_t)H_ * DQ_ * D_ * 2);
  u16* vwT = (u16*)alloc((size_t)H_ * DQ_ * D_ * 2);
  u16* owT = (u16*)alloc((size_t)D_ * D_ * 2);
  u16* w1T = (u16*)alloc((size_t)DF_ * D_ * 2);
  u16* w2T = (u16*)alloc((size_t)D_ * DF_ * 2);
  u16* src0b = (u16*)alloc((size_t)L_ * D_ * 2);
  u16* q0 = (u16*)alloc((size_t)H_ * L_ * DQ_ * 2);
  u16* k0 = (u16*)alloc((size_t)H_ * L_ * DQ_ * 2);
  u16* v0T = (u16*)alloc((size_t)H_ * DQ_ * L_ * 2);
  float* nzv = (float*)alloc((size_t)H_ * DM_ * 4);
  int* nzi = (int*)alloc((size_t)H_ * DM_ * 4);
  int* nzcnt = (int*)alloc(256);
  float* biasb = (float*)alloc((size_t)H_ * L_ * L_ * 4);
  float* attnvec = (float*)alloc((size_t)L_ * D_ * 4);
  u16* xb = (u16*)alloc((size_t)B_ * L_ * D_ * 2);
  u16* ffnh = (u16*)alloc((size_t)B_ * L_ * DF_ * 2);
  u16* yb = (u16*)alloc((size_t)B_ * L_ * D_ * 2);

  hipFuncSetAttribute((const void*)gemm8p<256, 1>,
                      hipFuncAttributeMaxDynamicSharedMemorySize, 131072);
  hipFuncSetAttribute((const void*)gemm8p<128, 2>,
                      hipFuncAttributeMaxDynamicSharedMemorySize, 98304);
  hipFuncSetAttribute((const void*)attnproj,
                      hipFuncAttributeMaxDynamicSharedMemorySize, 98304);

  const dim3 b256(256);
  // K1: qkv transposes + src b0 conversion + hid
  prep<<<dim3(3336), b256, 0, stream>>>(qw, kw, vw, src, sf, b1w, b1b, qwT, kwT,
                                        vwT, src0b, nzv, nzi, nzcnt);
  // K2: bias GEMV || QKV projections || ow/w1/w2 transposes
  phase2<<<dim3(9776), b256, 0, stream>>>(nzv, nzi, nzcnt, b2w, b2b, biasb, src0b,
                                          qwT, kwT, vwT, qb, kb, vb, q0, k0, v0T,
                                          ow, w1, w2, owT, w1T, w2T);
  // K3: fused attention + out projection -> attnvec [L][D] f32
  attnproj<<<dim3(16), dim3(512), 98304, stream>>>(q0, k0, v0T, biasb, mask, owT,
                                                   ob, attnvec);
  // K4: LN1 -> xb bf16
  ln_kernel<0><<<dim3(B_ * L_), b256, 0, stream>>>(src, attnvec, ln1g, ln1b, xb);
  // K5: FFN1 relu(x @ w1 + bf1) -> ffnh bf16
  gemm8p<256, 1><<<dim3(512), dim3(512), 131072, stream>>>(
      xb, w1T, ffnh, bf1, nullptr, B_ * L_, DF_, D_, DF_);
  // K6: FFN2 yb = bf16(ffnh @ w2 + bf2 + xb)
  gemm8p<128, 2><<<dim3(256), dim3(512), 98304, stream>>>(
      ffnh, w2T, yb, bf2, xb, B_ * L_, D_, DF_, D_);
  // K7: LN2 -> d_out (f32)
  ln_kernel<1><<<dim3(B_ * L_), b256, 0, stream>>>(yb, nullptr, ln2g, ln2b, out);
}

// Round 6
// 338.856 us; speedup vs baseline: 1.3952x; 1.0522x over previous
//
#include <hip/hip_runtime.h>

typedef unsigned short u16;
typedef short s16x8 __attribute__((ext_vector_type(8)));
typedef u16 u16x4 __attribute__((ext_vector_type(4)));
typedef float f32x4 __attribute__((ext_vector_type(4)));

#define B_ 32
#define L_ 256
#define D_ 1024
#define H_ 8
#define DQ_ 128
#define DS_ 64
#define DM_ 256
#define DF_ 4096

__device__ __forceinline__ u16 f2bf(float f) {
  unsigned u = __float_as_uint(f);
  unsigned r = (u + 0x7FFFu + ((u >> 16) & 1u)) >> 16;
  return (u16)r;
}
__device__ __forceinline__ float bf2f(u16 x) {
  return __uint_as_float(((unsigned)x) << 16);
}

__device__ __forceinline__ f32x4 mfma16(s16x8 a, s16x8 b, f32x4 c) {
  return __builtin_amdgcn_mfma_f32_16x16x32_bf16(a, b, c, 0, 0, 0);
}

#define GLDS16(g, l)                                                        \
  __builtin_amdgcn_global_load_lds(                                         \
      (__attribute__((address_space(1))) const void*)(g),                   \
      (__attribute__((address_space(3))) void*)(l), 16, 0, 0)

// ---------------- 32x32 transpose+convert tile helper
__device__ __forceinline__ void tile_tr(const float* __restrict__ ip,
                                        u16* __restrict__ op, int K, int N,
                                        int bx, int by, float (*t)[33], int tid) {
  const int tx = tid & 31, ty = tid >> 5;
  const long n0 = (long)bx * 32, k0 = (long)by * 32;
#pragma unroll
  for (int i = 0; i < 4; ++i)
    t[ty + i * 8][tx] = ip[(k0 + ty + i * 8) * (long)N + n0 + tx];
  __syncthreads();
#pragma unroll
  for (int i = 0; i < 4; ++i)
    op[(n0 + ty + i * 8) * (long)K + k0 + tx] = f2bf(t[tx][ty + i * 8]);
}

// ---------------- prep1: qkv transposes + src b0 conversion + hid
// grid: [0,3072) qkvT | [3072,3328) conv src b0 | [3328,3336) hid
__global__ __launch_bounds__(256) void prep1(
    const float* __restrict__ qw, const float* __restrict__ kw,
    const float* __restrict__ vw, const float* __restrict__ src,
    const float* __restrict__ sf, const float* __restrict__ b1w,
    const float* __restrict__ b1b, u16* __restrict__ qwT, u16* __restrict__ kwT,
    u16* __restrict__ vwT, u16* __restrict__ src0b, float* __restrict__ nzv,
    int* __restrict__ nzi, int* __restrict__ nzcnt) {
  const int b = blockIdx.x;
  const int tid = threadIdx.x;
  __shared__ float t[32][33];
  __shared__ float s_sf[DS_];
  __shared__ int wcnt[4];
  if (b < 3072) {
    const int z = b >> 7, rem = b & 127;
    const int sel = z >> 3, h = z & 7;
    const float* ip = (sel == 0 ? qw : (sel == 1 ? kw : vw)) + (long)h * D_ * DQ_;
    u16* op = (sel == 0 ? qwT : (sel == 1 ? kwT : vwT)) + (long)h * DQ_ * D_;
    tile_tr(ip, op, D_, DQ_, rem & 3, rem >> 2, t, tid);
  } else if (b < 3328) {
    const int rem = b - 3072;
    const int i = (rem * 256 + tid) * 4;
    float4 v = *(const float4*)(src + i);
    u16x4 o = {f2bf(v.x), f2bf(v.y), f2bf(v.z), f2bf(v.w)};
    *(u16x4*)(src0b + i) = o;
  } else {
    const int h = b - 3328;
    if (tid < DS_) s_sf[tid] = sf[tid];
    __syncthreads();
    float a = b1b[h * DM_ + tid];
    const float* wp = b1w + (long)h * DS_ * DM_ + tid;
#pragma unroll 8
    for (int s = 0; s < DS_; ++s) a += s_sf[s] * wp[s * DM_];
    a = fmaxf(a, 0.f);
    const unsigned long long bal = __ballot(a > 0.f);
    const int lane = tid & 63, wv = tid >> 6;
    const int pc = __popcll(bal);
    if (lane == 0) wcnt[wv] = pc;
    __syncthreads();
    int base = 0;
    for (int i = 0; i < wv; ++i) base += wcnt[i];
    const int pos = base + __popcll(bal & ((1ull << lane) - 1ull));
    if (a > 0.f) { nzv[h * DM_ + pos] = a; nzi[h * DM_ + pos] = tid; }
    if (tid == 255) nzcnt[h] = base + pc;
  }
}

// ---------------- prep2: qkv-proj [0,48) | owT [48,1072) | w1T [1072,5168) |
// w2T [5168,9264)
__global__ __launch_bounds__(256) void prep2(
    const u16* __restrict__ src0b, const u16* __restrict__ qwT,
    const u16* __restrict__ kwT, const u16* __restrict__ vwT,
    const float* __restrict__ qb, const float* __restrict__ kb,
    const float* __restrict__ vb, u16* __restrict__ q0, u16* __restrict__ k0,
    u16* __restrict__ v0T, const float* __restrict__ ow,
    const float* __restrict__ w1, const float* __restrict__ w2,
    u16* __restrict__ owT, u16* __restrict__ w1T, u16* __restrict__ w2T) {
  const int b = blockIdx.x;
  const int tid = threadIdx.x;
  __shared__ u16 smA[128 * 32];
  __shared__ u16 smB[128 * 32];
  __shared__ float t[32][33];
  if (b < 48) {
    const int r = b;
    const int z = r >> 1, sel = z >> 3, h = z & 7;
    const long tm = (long)(r & 1) * 128;
    const int K = D_;
    const u16* BT = (sel == 0 ? qwT : (sel == 1 ? kwT : vwT)) + (long)h * DQ_ * D_;
    const float* bias = (sel == 0 ? qb : (sel == 1 ? kb : vb)) + h * DQ_;
    const int lane = tid & 63;
    const int wv = tid >> 6;
    const int wr = wv >> 1, wc = wv & 1;
    const u16* ga = src0b + (tm + (tid >> 2)) * (long)K + (tid & 3) * 8;
    const u16* gb = BT + (long)(tid >> 2) * K + (tid & 3) * 8;
    const long rstep = 64L * K;
    u16* la = &smA[tid * 8];
    u16* lb = &smB[tid * 8];
    f32x4 acc[4][4];
#pragma unroll
    for (int m = 0; m < 4; ++m)
#pragma unroll
      for (int n = 0; n < 4; ++n) acc[m][n] = (f32x4){0.f, 0.f, 0.f, 0.f};
    for (int k0_ = 0; k0_ < K; k0_ += 32) {
      GLDS16(ga + k0_, la);
      GLDS16(ga + rstep + k0_, la + 64 * 32);
      GLDS16(gb + k0_, lb);
      GLDS16(gb + rstep + k0_, lb + 64 * 32);
      __syncthreads();
      s16x8 af[4], bf[4];
      const int ka = (lane >> 4) * 8;
      const int ra = wr * 64 + (lane & 15);
      const int rb = wc * 64 + (lane & 15);
#pragma unroll
      for (int m = 0; m < 4; ++m) af[m] = *(const s16x8*)&smA[(ra + m * 16) * 32 + ka];
#pragma unroll
      for (int n = 0; n < 4; ++n) bf[n] = *(const s16x8*)&smB[(rb + n * 16) * 32 + ka];
#pragma unroll
      for (int m = 0; m < 4; ++m)
#pragma unroll
        for (int n = 0; n < 4; ++n) acc[m][n] = mfma16(af[m], bf[n], acc[m][n]);
      __syncthreads();
    }
    const long crow0 = tm + wr * 64 + ((lane >> 4) * 4);
    const long ccol0 = wc * 64 + (lane & 15);
#pragma unroll
    for (int m = 0; m < 4; ++m)
#pragma unroll
      for (int n = 0; n < 4; ++n)
#pragma unroll
        for (int i = 0; i < 4; ++i) {
          const long row = crow0 + m * 16 + i;
          const long col = ccol0 + n * 16;
          const float v = acc[m][n][i] + bias[col];
          if (sel < 2) {
            u16* o = (sel == 0 ? q0 : k0) + (long)h * L_ * DQ_;
            o[row * DQ_ + col] = f2bf(v);
          } else {
            v0T[(long)h * DQ_ * L_ + col * L_ + row] = f2bf(v);
          }
        }
  } else if (b < 1072) {
    const int rem = b - 48;
    tile_tr(ow, owT, D_, D_, rem & 31, rem >> 5, t, tid);
  } else if (b < 5168) {
    const int rem = b - 1072;
    tile_tr(w1, w1T, D_, DF_, rem & 127, rem >> 7, t, tid);
  } else {
    const int rem = b - 5168;
    tile_tr(w2, w2T, DF_, D_, rem & 31, rem >> 5, t, tid);
  }
}

// ---------------- phase2b: gemv [0,512) -> biasb16 (bf16) | attn-soft [512,544)
// attn: 4 independent waves per block; wave task = (b-512)*4+w : h=task>>4, rt=task&15
__global__ __launch_bounds__(256) void phase2b(
    const float* __restrict__ nzv, const int* __restrict__ nzi,
    const int* __restrict__ nzcnt, const float* __restrict__ b2w,
    const float* __restrict__ b2b, u16* __restrict__ biasb16,
    const u16* __restrict__ q0, const u16* __restrict__ k0,
    const u16* __restrict__ v0T, const int* __restrict__ mask,
    u16* __restrict__ hidden) {
  extern __shared__ char shm[];
  const int b = blockIdx.x;
  const int tid = threadIdx.x;
  if (b < 512) {
    float* sv = (float*)shm;
    int* si = (int*)(shm + 1024);
    const int h = b >> 6;
    const int n0 = (b & 63) << 10;
    const int nnz = nzcnt[h];
    if (tid < DM_) { sv[tid] = nzv[h * DM_ + tid]; si[tid] = nzi[h * DM_ + tid]; }
    __syncthreads();
    const float* wb = b2w + (long)h * DM_ * 65536 + n0 + tid * 4;
    float4 acc = {0.f, 0.f, 0.f, 0.f};
    int j = 0;
    for (; j + 4 <= nnz; j += 4) {
      const float4 a0 = *(const float4*)(wb + (long)si[j] * 65536);
      const float4 a1 = *(const float4*)(wb + (long)si[j + 1] * 65536);
      const float4 a2 = *(const float4*)(wb + (long)si[j + 2] * 65536);
      const float4 a3 = *(const float4*)(wb + (long)si[j + 3] * 65536);
      const float v0 = sv[j], v1 = sv[j + 1], v2 = sv[j + 2], v3 = sv[j + 3];
      acc.x += v0 * a0.x + v1 * a1.x + v2 * a2.x + v3 * a3.x;
      acc.y += v0 * a0.y + v1 * a1.y + v2 * a2.y + v3 * a3.y;
      acc.z += v0 * a0.z + v1 * a1.z + v2 * a2.z + v3 * a3.z;
      acc.w += v0 * a0.w + v1 * a1.w + v2 * a2.w + v3 * a3.w;
    }
    for (; j < nnz; ++j) {
      const float4 a0 = *(const float4*)(wb + (long)si[j] * 65536);
      const float v0 = sv[j];
      acc.x += v0 * a0.x; acc.y += v0 * a0.y; acc.z += v0 * a0.z; acc.w += v0 * a0.w;
    }
    const float4 bb = *(const float4*)(b2b + (long)h * 65536 + n0 + tid * 4);
    u16x4 o = {f2bf(acc.x + bb.x), f2bf(acc.y + bb.y), f2bf(acc.z + bb.z),
               f2bf(acc.w + bb.w)};
    *(u16x4*)(biasb16 + (long)h * 65536 + n0 + tid * 4) = o;
  } else {
    const int w = tid >> 6;
    const int task = (b - 512) * 4 + w;
    const int h = task >> 4;
    const int r0 = (task & 15) << 4;
    const int lane = tid & 63;
    const int lg = lane >> 4;
    const int ll = lane & 15;
    const u16* q = q0 + (long)h * L_ * DQ_;
    const u16* k = k0 + (long)h * L_ * DQ_;
    const u16* v = v0T + (long)h * DQ_ * L_;
    char* pbuf = shm + w * 8192;  // [16 rows][256 cols] u16, XOR-swizzled

    s16x8 aq[4];
#pragma unroll
    for (int kk = 0; kk < 4; ++kk)
      aq[kk] = *(const s16x8*)(q + (long)(r0 + ll) * DQ_ + kk * 32 + lg * 8);
    float sc[16][4];
    const float scale = 0.08838834764831845f;  // 1/sqrt(128)
#pragma unroll
    for (int t = 0; t < 16; ++t) {
      f32x4 a = {0.f, 0.f, 0.f, 0.f};
#pragma unroll
      for (int kk = 0; kk < 4; ++kk) {
        s16x8 bf = *(const s16x8*)(k + (long)(t * 16 + ll) * DQ_ + kk * 32 + lg * 8);
        a = mfma16(aq[kk], bf, a);
      }
#pragma unroll
      for (int i = 0; i < 4; ++i) {
        const int row = r0 + lg * 4 + i;
        const int col = t * 16 + ll;
        float s = a[i] * scale;
        if (mask[row * L_ + col] != 0) s = 1e-9f;
        sc[t][i] = s;
      }
    }
#pragma unroll
    for (int i = 0; i < 4; ++i) {
      float mx = sc[0][i];
#pragma unroll
      for (int t = 1; t < 16; ++t) mx = fmaxf(mx, sc[t][i]);
#pragma unroll
      for (int d = 1; d < 16; d <<= 1) mx = fmaxf(mx, __shfl_xor(mx, d));
      float sum = 0.f;
#pragma unroll
      for (int t = 0; t < 16; ++t) {
        const float e = __expf(sc[t][i] - mx);
        sc[t][i] = e;
        sum += e;
      }
#pragma unroll
      for (int d = 1; d < 16; d <<= 1) sum += __shfl_xor(sum, d);
      const float inv = 1.f / sum;
#pragma unroll
      for (int t = 0; t < 16; ++t) sc[t][i] *= inv;  // NO bias (handled by biaspv)
    }
    // write P (bf16) swizzled
#pragma unroll
    for (int t = 0; t < 16; ++t)
#pragma unroll
      for (int i = 0; i < 4; ++i) {
        const int lr = lg * 4 + i;
        const int cb = (t * 16 + ll) * 2;
        *(u16*)(pbuf + lr * 512 + (cb ^ ((lr & 7) << 4))) = f2bf(sc[t][i]);
      }
    // PV
    s16x8 paf[8];
#pragma unroll
    for (int kk = 0; kk < 8; ++kk)
      paf[kk] = *(const s16x8*)(pbuf + ll * 512 + ((kk * 64 + lg * 16) ^ ((ll & 7) << 4)));
#pragma unroll
    for (int n = 0; n < 8; ++n) {
      f32x4 a = {0.f, 0.f, 0.f, 0.f};
#pragma unroll
      for (int kk = 0; kk < 8; ++kk) {
        s16x8 bf = *(const s16x8*)(v + (long)(n * 16 + ll) * 256 + kk * 32 + lg * 8);
        a = mfma16(paf[kk], bf, a);
      }
#pragma unroll
      for (int i = 0; i < 4; ++i) {
        const int row = r0 + lg * 4 + i;
        const int col = n * 16 + ll;
        hidden[(long)row * 1024 + h * 128 + col] = f2bf(a[i]);
      }
    }
  }
}

// ---------------- shared 128x128xK m97 GEMM core (A,BT pre-offset to tile)
__device__ __forceinline__ void g128_core(const u16* __restrict__ A,
                                          const u16* __restrict__ BT, int K,
                                          u16* smA, u16* smB,
                                          f32x4 (&acc)[4][4]) {
  const int tid = threadIdx.x;
  const int lane = tid & 63;
  const int wv = tid >> 6;
  const int wr = wv >> 1, wc = wv & 1;
  const u16* ga = A + (long)(tid >> 2) * K + (tid & 3) * 8;
  const u16* gb = BT + (long)(tid >> 2) * K + (tid & 3) * 8;
  const long rstep = 64L * K;
  u16* la = &smA[tid * 8];
  u16* lb = &smB[tid * 8];
#pragma unroll
  for (int m = 0; m < 4; ++m)
#pragma unroll
    for (int n = 0; n < 4; ++n) acc[m][n] = (f32x4){0.f, 0.f, 0.f, 0.f};
  for (int k0 = 0; k0 < K; k0 += 32) {
    GLDS16(ga + k0, la);
    GLDS16(ga + rstep + k0, la + 64 * 32);
    GLDS16(gb + k0, lb);
    GLDS16(gb + rstep + k0, lb + 64 * 32);
    __syncthreads();
    s16x8 af[4], bf[4];
    const int ka = (lane >> 4) * 8;
    const int ra = wr * 64 + (lane & 15);
    const int rb = wc * 64 + (lane & 15);
#pragma unroll
    for (int m = 0; m < 4; ++m) af[m] = *(const s16x8*)&smA[(ra + m * 16) * 32 + ka];
#pragma unroll
    for (int n = 0; n < 4; ++n) bf[n] = *(const s16x8*)&smB[(rb + n * 16) * 32 + ka];
#pragma unroll
    for (int m = 0; m < 4; ++m)
#pragma unroll
      for (int n = 0; n < 4; ++n) acc[m][n] = mfma16(af[m], bf[n], acc[m][n]);
    __syncthreads();
  }
}

// ---------------- biaspv: hidden += biasb16 @ V  (grid (2 row-tiles, 8 heads))
__global__ __launch_bounds__(256) void biaspv(
    const u16* __restrict__ biasb16, const u16* __restrict__ v0T,
    u16* __restrict__ hidden) {
  __shared__ u16 smA[128 * 32];
  __shared__ u16 smB[128 * 32];
  const int tid = threadIdx.x;
  const int rt = blockIdx.x, h = blockIdx.y;
  f32x4 acc[4][4];
  g128_core(biasb16 + (long)h * 65536 + (long)rt * 128 * 256,
            v0T + (long)h * DQ_ * L_, 256, smA, smB, acc);
  const int lane = tid & 63;
  const int wv = tid >> 6;
  const int wr = wv >> 1, wc = wv & 1;
  const long crow0 = (long)rt * 128 + wr * 64 + ((lane >> 4) * 4);
  const long ccol0 = wc * 64 + (lane & 15);
#pragma unroll
  for (int m = 0; m < 4; ++m)
#pragma unroll
    for (int n = 0; n < 4; ++n)
#pragma unroll
      for (int i = 0; i < 4; ++i) {
        const long row = crow0 + m * 16 + i;
        const long col = ccol0 + n * 16;
        u16* p = hidden + row * 1024 + h * 128 + col;
        *p = f2bf(acc[m][n][i] + bf2f(*p));
      }
}

// ---------------- m97-style 128x128 GEMM, f32 out +bias (attn out proj)
__global__ __launch_bounds__(256) void gemm_bt(
    const u16* __restrict__ A, const u16* __restrict__ BT, float* __restrict__ C,
    const float* __restrict__ bias, int K, int ldc) {
  __shared__ u16 smA[128 * 32];
  __shared__ u16 smB[128 * 32];
  const int tid = threadIdx.x;
  const long tm = (long)blockIdx.x * 128;
  const long tn = (long)blockIdx.y * 128;
  f32x4 acc[4][4];
  g128_core(A + tm * K, BT + tn * K, K, smA, smB, acc);
  const int lane = tid & 63;
  const int wv = tid >> 6;
  const int wr = wv >> 1, wc = wv & 1;
  const long crow0 = tm + wr * 64 + ((lane >> 4) * 4);
  const long ccol0 = tn + wc * 64 + (lane & 15);
#pragma unroll
  for (int m = 0; m < 4; ++m)
#pragma unroll
    for (int n = 0; n < 4; ++n)
#pragma unroll
      for (int i = 0; i < 4; ++i) {
        const long row = crow0 + m * 16 + i;
        const long col = ccol0 + n * 16;
        C[row * (long)ldc + col] = acc[m][n][i] + bias[col];
      }
}

// ---------------- 8-phase 256xBN deep-pipelined GEMM (T1+T2+T4+T5)
// EPI: 1 = bf16 out relu(+bias); 2 = bf16 out +bias +bf16 residual
template <int BN, int EPI>
__global__ __launch_bounds__(512, 2) void gemm8p(
    const u16* __restrict__ A, const u16* __restrict__ BT, void* __restrict__ Cv,
    const float* __restrict__ bias, const void* __restrict__ R, int M, int N,
    int K, int ldc) {
  extern __shared__ char lds[];
  constexpr int NR = BN / 64;
  constexpr int NHB = BN / 128;
  constexpr int BUF = 32768 + BN * 128;
  constexpr int WST = (NHB == 2) ? 4 : 2;
  const int tid = threadIdx.x;
  const int lane = tid & 63;
  const int w = tid >> 6;
  const int wr = w >> 2, wc = w & 3;

  const int total = gridDim.x;
  int bid = blockIdx.x;
  int s = ((total & 7) == 0) ? ((bid & 7) * (total >> 3) + (bid >> 3)) : bid;
  const int gn = N / BN;
  const long tm = (long)(s / gn) * 256;
  const long tn = (long)(s % gn) * BN;
  const int NT = K >> 6;

  auto stageA = [&](int half, int t) {
    char* hb = lds + (long)(t & 1) * BUF + half * 16384;
    const u16* g = A + (tm + half * 128) * (long)K + (long)t * 64;
#pragma unroll
    for (int j = 0; j < 2; ++j) {
      const int idx = j * 512 + tid;
      const int r = idx >> 3;
      const int c16 = (idx & 7) ^ (r & 7);
      GLDS16(g + (long)r * K + c16 * 8, hb + idx * 16);
    }
  };
  auto stageB = [&](int half, int t) {
    char* hb = lds + (long)(t & 1) * BUF + 32768 + half * 16384;
    const u16* g = BT + (tn + half * 128) * (long)K + (long)t * 64;
#pragma unroll
    for (int j = 0; j < 2; ++j) {
      const int idx = j * 512 + tid;
      const int r = idx >> 3;
      const int c16 = (idx & 7) ^ (r & 7);
      GLDS16(g + (long)r * K + c16 * 8, hb + idx * 16);
    }
  };

  stageA(0, 0);
  stageA(1, 0);
  stageB(0, 0);
  if (NHB == 2) stageB(1, 0);
  stageB(0, 1);
  if (NHB == 2) stageB(1, 1);
  asm volatile("s_waitcnt vmcnt(%0)" ::"n"(WST) : "memory");
  __builtin_amdgcn_s_barrier();

  f32x4 acc[8][NR];
#pragma unroll
  for (int m = 0; m < 8; ++m)
#pragma unroll
    for (int n = 0; n < NR; ++n) acc[m][n] = (f32x4){0.f, 0.f, 0.f, 0.f};

  const int lk = (lane >> 4) * 16;
  const int lr = lane & 15;

  for (int t = 0; t < NT; ++t) {
    const char* bp = lds + (long)(t & 1) * BUF;
    s16x8 bfr[NR][2];
#pragma unroll
    for (int p = 0; p < 4; ++p) {
      if (p == 0) {
#pragma unroll
        for (int ni = 0; ni < NR; ++ni) {
          const int brow = wc * (BN / 4) + ni * 16 + lr;
#pragma unroll
          for (int ks = 0; ks < 2; ++ks) {
            const int kb = (ks * 64 + lk) ^ ((brow & 7) << 4);
            bfr[ni][ks] = *(const s16x8*)(bp + 32768 + brow * 128 + kb);
          }
        }
      }
      s16x8 afr[2][2];
#pragma unroll
      for (int rI = 0; rI < 2; ++rI) {
        const int arow = wr * 128 + (2 * p + rI) * 16 + lr;
#pragma unroll
        for (int ks = 0; ks < 2; ++ks) {
          const int kb = (ks * 64 + lk) ^ ((arow & 7) << 4);
          afr[rI][ks] = *(const s16x8*)(bp + arow * 128 + kb);
        }
      }
      if (p == 0) { if (t + 1 < NT) stageA(0, t + 1); }
      else if (p == 1) { if (t + 1 < NT) stageA(1, t + 1); }
      else if (p == 2) { if (t + 2 < NT) stageB(0, t + 2); }
      else { if (NHB == 2 && t + 2 < NT) stageB(1, t + 2); }
      __builtin_amdgcn_s_barrier();
      __builtin_amdgcn_s_setprio(1);
#pragma unroll
      for (int rI = 0; rI < 2; ++rI)
#pragma unroll
        for (int ni = 0; ni < NR; ++ni)
#pragma unroll
          for (int ks = 0; ks < 2; ++ks)
            acc[2 * p + rI][ni] = mfma16(afr[rI][ks], bfr[ni][ks], acc[2 * p + rI][ni]);
      __builtin_amdgcn_s_setprio(0);
      if (p == 3) {
        if (t + 2 < NT) {
          asm volatile("s_waitcnt vmcnt(%0)" ::"n"(WST) : "memory");
        } else if (t + 1 < NT) {
          asm volatile("s_waitcnt vmcnt(0)" ::: "memory");
        }
      }
      __builtin_amdgcn_s_barrier();
    }
  }

  const long crow0 = tm + wr * 128 + ((lane >> 4) * 4);
  const long ccol0 = tn + wc * (BN / 4) + lr;
#pragma unroll
  for (int m = 0; m < 8; ++m) {
#pragma unroll
    for (int n = 0; n < NR; ++n) {
#pragma unroll
      for (int i = 0; i < 4; ++i) {
        const long row = crow0 + m * 16 + i;
        const long col = ccol0 + n * 16;
        const float v = acc[m][n][i] + bias[col];
        if constexpr (EPI == 1) {
          ((u16*)Cv)[row * (long)ldc + col] = f2bf(fmaxf(v, 0.f));
        } else {
          const float r = bf2f(((const u16*)R)[row * (long)ldc + col]);
          ((u16*)Cv)[row * (long)ldc + col] = f2bf(v + r);
        }
      }
    }
  }
}

// ---------------- layernorm over D=1024
// MODE 0: in f32 + add f32 (attn row, row%L), out bf16
// MODE 1: in bf16, out f32
template <int MODE>
__global__ __launch_bounds__(256) void ln_kernel(
    const void* __restrict__ in0v, const float* __restrict__ add1,
    const float* __restrict__ g, const float* __restrict__ bb,
    void* __restrict__ outv) {
  const int tid = threadIdx.x;
  const long row = blockIdx.x;
  float4 v;
  if constexpr (MODE == 0) {
    v = ((const float4*)((const float*)in0v + row * D_))[tid];
    const float4 u = ((const float4*)(add1 + (row & (L_ - 1)) * D_))[tid];
    v.x += u.x; v.y += u.y; v.z += u.z; v.w += u.w;
  } else {
    const uint2 pk = *(const uint2*)((const u16*)in0v + row * D_ + tid * 4);
    v.x = __uint_as_float((pk.x & 0xFFFFu) << 16);
    v.y = __uint_as_float(pk.x & 0xFFFF0000u);
    v.z = __uint_as_float((pk.y & 0xFFFFu) << 16);
    v.w = __uint_as_float(pk.y & 0xFFFF0000u);
  }
  float s = v.x + v.y + v.z + v.w;
  float q = v.x * v.x + v.y * v.y + v.z * v.z + v.w * v.w;
#pragma unroll
  for (int d = 1; d < 64; d <<= 1) { s += __shfl_xor(s, d); q += __shfl_xor(q, d); }
  __shared__ float ss[4], sq[4];
  const int wv = tid >> 6;
  if ((tid & 63) == 0) { ss[wv] = s; sq[wv] = q; }
  __syncthreads();
  s = ss[0] + ss[1] + ss[2] + ss[3];
  q = sq[0] + sq[1] + sq[2] + sq[3];
  const float mu = s * (1.f / D_);
  const float var = q * (1.f / D_) - mu * mu;
  const float rs = rsqrtf(var + 1e-5f);
  const float4 gv = ((const float4*)g)[tid];
  const float4 bv = ((const float4*)bb)[tid];
  float4 o;
  o.x = (v.x - mu) * rs * gv.x + bv.x;
  o.y = (v.y - mu) * rs * gv.y + bv.y;
  o.z = (v.z - mu) * rs * gv.z + bv.z;
  o.w = (v.w - mu) * rs * gv.w + bv.w;
  if constexpr (MODE == 0) {
    uint2 pk;
    pk.x = (unsigned)f2bf(o.x) | ((unsigned)f2bf(o.y) << 16);
    pk.y = (unsigned)f2bf(o.z) | ((unsigned)f2bf(o.w) << 16);
    *(uint2*)((u16*)outv + row * D_ + tid * 4) = pk;
  } else {
    ((float4*)((float*)outv + row * D_))[tid] = o;
  }
}

extern "C" void kernel_launch(void* const* d_in, const int* in_sizes, int n_in,
                              void* d_out, int out_size, void* d_ws, size_t ws_size,
                              hipStream_t stream) {
  (void)in_sizes; (void)n_in; (void)out_size; (void)ws_size;
  const float* src = (const float*)d_in[0];
  const float* sf = (const float*)d_in[1];
  const int* mask = (const int*)d_in[2];
  const float* qw = (const float*)d_in[3];
  const float* qb = (const float*)d_in[4];
  const float* kw = (const float*)d_in[5];
  const float* kb = (const float*)d_in[6];
  const float* vw = (const float*)d_in[7];
  const float* vb = (const float*)d_in[8];
  const float* b1w = (const float*)d_in[9];
  const float* b1b = (const float*)d_in[10];
  const float* b2w = (const float*)d_in[11];
  const float* b2b = (const float*)d_in[12];
  const float* ow = (const float*)d_in[13];
  const float* ob = (const float*)d_in[14];
  const float* ln1g = (const float*)d_in[15];
  const float* ln1b = (const float*)d_in[16];
  const float* ln2g = (const float*)d_in[17];
  const float* ln2b = (const float*)d_in[18];
  const float* w1 = (const float*)d_in[19];
  const float* bf1 = (const float*)d_in[20];
  const float* w2 = (const float*)d_in[21];
  const float* bf2 = (const float*)d_in[22];
  float* out = (float*)d_out;

  char* ws = (char*)d_ws;
  size_t off = 0;
  auto alloc = [&](size_t bytes) {
    void* p = ws + off;
    off += (bytes + 255) & ~(size_t)255;
    return p;
  };
  u16* qwT = (u16*)alloc((size_t)H_ * DQ_ * D_ * 2);
  u16* kwT = (u16*)alloc((size_t)H_ * DQ_ * D_ * 2);
  u16* vwT = (u16*)alloc((size_t)H_ * DQ_ * D_ * 2);
  u16* owT = (u16*)alloc((size_t)D_ * D_ * 2);
  u16* w1T = (u16*)alloc((size_t)DF_ * D_ * 2);
  u16* w2T = (u16*)alloc((size_t)D_ * DF_ * 2);
  u16* src0b = (u16*)alloc((size_t)L_ * D_ * 2);
  u16* q0 = (u16*)alloc((size_t)H_ * L_ * DQ_ * 2);
  u16* k0 = (u16*)alloc((size_t)H_ * L_ * DQ_ * 2);
  u16* v0T = (u16*)alloc((size_t)H_ * DQ_ * L_ * 2);
  float* nzv = (float*)alloc((size_t)H_ * DM_ * 4);
  int* nzi = (int*)alloc((size_t)H_ * DM_ * 4);
  int* nzcnt = (int*)alloc(256);
  u16* biasb16 = (u16*)alloc((size_t)H_ * L_ * L_ * 2);
  u16* hidden = (u16*)alloc((size_t)L_ * D_ * 2);
  float* attnvec = (float*)alloc((size_t)L_ * D_ * 4);
  u16* xb = (u16*)alloc((size_t)B_ * L_ * D_ * 2);
  u16* ffnh = (u16*)alloc((size_t)B_ * L_ * DF_ * 2);
  u16* yb = (u16*)alloc((size_t)B_ * L_ * D_ * 2);

  hipFuncSetAttribute((const void*)gemm8p<256, 1>,
                      hipFuncAttributeMaxDynamicSharedMemorySize, 131072);
  hipFuncSetAttribute((const void*)gemm8p<128, 2>,
                      hipFuncAttributeMaxDynamicSharedMemorySize, 98304);

  const dim3 b256(256);
  // K1: qkv weight transposes + src b0 conversion + hid nz-compaction
  prep1<<<dim3(3336), b256, 0, stream>>>(qw, kw, vw, src, sf, b1w, b1b, qwT, kwT,
                                         vwT, src0b, nzv, nzi, nzcnt);
  // K2: qkv projections || ow/w1/w2 transposes
  prep2<<<dim3(9264), b256, 0, stream>>>(src0b, qwT, kwT, vwT, qb, kb, vb, q0, k0,
                                         v0T, ow, w1, w2, owT, w1T, w2T);
  // K3: bias GEMV (-> bf16) || bias-free attention -> hidden
  phase2b<<<dim3(544), b256, 32768, stream>>>(nzv, nzi, nzcnt, b2w, b2b, biasb16,
                                              q0, k0, v0T, mask, hidden);
  // K4: hidden += biasb16 @ V
  biaspv<<<dim3(2, 8), b256, 0, stream>>>(biasb16, v0T, hidden);
  // K5: attn out projection -> attnvec f32
  gemm_bt<<<dim3(2, 8), b256, 0, stream>>>(hidden, owT, attnvec, ob, D_, D_);
  // K6: LN1 -> xb bf16
  ln_kernel<0><<<dim3(B_ * L_), b256, 0, stream>>>(src, attnvec, ln1g, ln1b, xb);
  // K7: FFN1 relu(x @ w1 + bf1) -> ffnh bf16
  gemm8p<256, 1><<<dim3(512), dim3(512), 131072, stream>>>(
      xb, w1T, ffnh, bf1, nullptr, B_ * L_, DF_, D_, DF_);
  // K8: FFN2 yb = bf16(ffnh @ w2 + bf2 + xb)
  gemm8p<128, 2><<<dim3(256), dim3(512), 98304, stream>>>(
      ffnh, w2T, yb, bf2, xb, B_ * L_, D_, DF_, D_);
  // K9: LN2 -> d_out (f32)
  ln_kernel<1><<<dim3(B_ * L_), b256, 0, stream>>>(yb, nullptr, ln2g, ln2b, out);
}